// Round 12
// baseline (5117.269 us; speedup 1.0000x reference)
//
#include <hip/hip_runtime.h>
#include <cstddef>

#define NN 883
#define BB 64
#define TT 12
#define EMB 10
#define KPAD 896  // node dim padded to multiple of 128

typedef short short8 __attribute__((ext_vector_type(8)));
typedef _Float16 half8 __attribute__((ext_vector_type(8)));
typedef float f32x4 __attribute__((ext_vector_type(4)));

__device__ __forceinline__ void split_f16(float v, _Float16* hp, _Float16* lp) {
  _Float16 h = (_Float16)v;
  *hp = h;
  *lp = (_Float16)(v - (float)h);
}

// -------- adjacency: A = softmax(relu(E E^T), axis=1), emitted as f16 hi/lo --
__global__ __launch_bounds__(256) void adj_kernel(const float* __restrict__ E,
                                                  _Float16* __restrict__ Ah,
                                                  _Float16* __restrict__ Al) {
  const int n = blockIdx.x;
  const int tid = threadIdx.x;
  __shared__ float sE[EMB];
  __shared__ float sred[256];
  if (tid < EMB) sE[tid] = E[n * EMB + tid];
  __syncthreads();
  float d[4];
  float lmax = 0.0f;
#pragma unroll
  for (int q = 0; q < 4; ++q) {
    int m = tid + q * 256;
    d[q] = 0.0f;
    if (m < NN) {
      float s = 0.0f;
#pragma unroll
      for (int e = 0; e < EMB; ++e) s += sE[e] * E[m * EMB + e];
      d[q] = fmaxf(s, 0.0f);
      lmax = fmaxf(lmax, d[q]);
    }
  }
  sred[tid] = lmax;
  __syncthreads();
  for (int s = 128; s > 0; s >>= 1) {
    if (tid < s) sred[tid] = fmaxf(sred[tid], sred[tid + s]);
    __syncthreads();
  }
  const float mx = sred[0];
  __syncthreads();
  float lsum = 0.0f;
#pragma unroll
  for (int q = 0; q < 4; ++q) {
    int m = tid + q * 256;
    if (m < NN) {
      d[q] = expf(d[q] - mx);
      lsum += d[q];
    }
  }
  sred[tid] = lsum;
  __syncthreads();
  for (int s = 128; s > 0; s >>= 1) {
    if (tid < s) sred[tid] += sred[tid + s];
    __syncthreads();
  }
  const float inv = 1.0f / sred[0];
#pragma unroll
  for (int q = 0; q < 4; ++q) {
    int m = tid + q * 256;
    if (m < KPAD) {
      float v = (m < NN) ? d[q] * inv : 0.0f;
      split_f16(v, &Ah[(size_t)n * KPAD + m], &Al[(size_t)n * KPAD + m]);
    }
  }
}

// -------- 3-term split-f16 MFMA GEMM; output written as split f16 ------------
__global__ __launch_bounds__(256) void mfma_gemm3(const _Float16* __restrict__ Ah,
                                                  const _Float16* __restrict__ Al,
                                                  const _Float16* __restrict__ Xh,
                                                  const _Float16* __restrict__ Xl,
                                                  _Float16* __restrict__ Gh,
                                                  _Float16* __restrict__ Gl, int L) {
  __shared__ _Float16 sA[2][128][40];
  __shared__ _Float16 sX[2][4][128][8];
  const int tid = threadIdx.x;
  const int lane = tid & 63;
  const int wid = tid >> 6;
  const int wm = (wid >> 1) * 64, wn = (wid & 1) * 64;
  const int bm = blockIdx.y * 128;
  const int bl = blockIdx.x * 128;
  const int l15 = lane & 15, l4 = lane >> 4;

  f32x4 acc[4][4] = {};

  const int xlp = (tid & 63) * 2;
  const int xko = tid >> 6;

  for (int k0 = 0; k0 < KPAD; k0 += 32) {
    __syncthreads();
#pragma unroll
    for (int p = 0; p < 2; ++p) {
      int i = tid + p * 256;
      int m = i >> 2, k8 = (i & 3) * 8;
      *(half8*)&sA[0][m][k8] = *(const half8*)&Ah[(size_t)(bm + m) * KPAD + k0 + k8];
      *(half8*)&sA[1][m][k8] = *(const half8*)&Al[(size_t)(bm + m) * KPAD + k0 + k8];
    }
    {
      int gl = bl + xlp;
      int kb = k0 + xko * 8;
#pragma unroll
      for (int buf = 0; buf < 2; ++buf) {
        const _Float16* Xp = buf ? Xl : Xh;
        unsigned int v[8];
#pragma unroll
        for (int j = 0; j < 8; ++j)
          v[j] = *(const unsigned int*)&Xp[(size_t)(kb + j) * L + gl];
        short8 lo, hi;
#pragma unroll
        for (int j = 0; j < 8; ++j) {
          lo[j] = (short)(v[j] & 0xFFFFu);
          hi[j] = (short)(v[j] >> 16);
        }
        *(short8*)&sX[buf][xko][xlp][0] = lo;
        *(short8*)&sX[buf][xko][xlp + 1][0] = hi;
      }
    }
    __syncthreads();
    half8 afh[4], afl[4], bfh[4], bfl[4];
#pragma unroll
    for (int mi = 0; mi < 4; ++mi) {
      afh[mi] = *(half8*)&sA[0][wm + mi * 16 + l15][l4 * 8];
      afl[mi] = *(half8*)&sA[1][wm + mi * 16 + l15][l4 * 8];
    }
#pragma unroll
    for (int ni = 0; ni < 4; ++ni) {
      bfh[ni] = *(half8*)&sX[0][l4][wn + ni * 16 + l15][0];
      bfl[ni] = *(half8*)&sX[1][l4][wn + ni * 16 + l15][0];
    }
#pragma unroll
    for (int mi = 0; mi < 4; ++mi)
#pragma unroll
      for (int ni = 0; ni < 4; ++ni) {
        acc[mi][ni] = __builtin_amdgcn_mfma_f32_16x16x32_f16(afh[mi], bfh[ni],
                                                             acc[mi][ni], 0, 0, 0);
        acc[mi][ni] = __builtin_amdgcn_mfma_f32_16x16x32_f16(afh[mi], bfl[ni],
                                                             acc[mi][ni], 0, 0, 0);
        acc[mi][ni] = __builtin_amdgcn_mfma_f32_16x16x32_f16(afl[mi], bfh[ni],
                                                             acc[mi][ni], 0, 0, 0);
      }
  }
#pragma unroll
  for (int mi = 0; mi < 4; ++mi) {
    int row0 = bm + wm + mi * 16 + l4 * 4;
#pragma unroll
    for (int ni = 0; ni < 4; ++ni) {
      int col = bl + wn + ni * 16 + l15;
#pragma unroll
      for (int r = 0; r < 4; ++r) {
        int row = row0 + r;
        if (row < NN)
          split_f16(acc[mi][ni][r], &Gh[(size_t)row * L + col],
                    &Gl[(size_t)row * L + col]);
      }
    }
  }
}

// -------- build Xs: all 12 steps' x, octet-major [n][t][b][8] (j=0 only) -----
__global__ __launch_bounds__(256) void srcall_kernel(const float* __restrict__ src,
                                                     _Float16* __restrict__ Xsh,
                                                     _Float16* __restrict__ Xsl) {
  int i = blockIdx.x * 256 + threadIdx.x;
  if (i >= NN * BB * TT) return;
  int t = i % TT;
  int nb = i / TT;
  int b = nb & 63, n = nb >> 6;
  float v = src[((size_t)b * TT + t) * NN + n];
  size_t idx = (size_t)n * (TT * 512) + (size_t)t * 512 + (size_t)b * 8;
  split_f16(v, &Xsh[idx], &Xsl[idx]);
}

// -------- W-gen helper: fused per-node weights for octets [kob, kob+kch) -----
template <int CS, int CIN, int XSPLIT, int COUT>
__device__ __forceinline__ void wgen_chunk(int kob, int kch, const float* sE,
                                           const float* __restrict__ wpool,
                                           int och, int tid,
                                           _Float16* __restrict__ dWh,
                                           _Float16* __restrict__ dWl) {
  constexpr int KD = 2 * CS;
  const int o = tid & 63;
  for (int kol = tid >> 6; kol < kch; kol += 4) {
    const int ko = kob + kol;
    half8 hv, lv;
#pragma unroll
    for (int j = 0; j < 8; ++j) {
      const int k = ko * 8 + j;
      float w = 0.0f;
      if (k < KD) {
        const int kk = (k >= CS) ? 1 : 0;
        const int kc = k - kk * CS;
        int ii;
        if (CS == CIN) ii = kc;
        else ii = (kc == 0) ? 0 : ((kc >= XSPLIT) ? kc - XSPLIT + 1 : -1);
        if (ii >= 0) {
          const float* wp = wpool + ((size_t)kk * CIN + ii) * COUT + och + o;
#pragma unroll
          for (int d = 0; d < EMB; ++d)
            w += sE[d] * wp[(size_t)d * (2 * CIN * COUT)];
        }
      }
      _Float16 hh = (_Float16)w;
      hv[j] = hh;
      lv[j] = (_Float16)(w - (float)hh);
    }
    *(half8*)&dWh[((size_t)kol * 64 + o) * 8] = hv;
    *(half8*)&dWl[((size_t)kol * 64 + o) * 8] = lv;
  }
}

// -------- fused per-node gconv: double-buffered chunked W-gen + MFMA ---------
// All operand buffers octet-major per node: [n][ko][b][8], channel = ko*8+j.
// K regions: [0,XSPLIT) IX; [XSPLIT,CS) IZ; [CS,CS+XSPLIT) DX; [CS+XSPLIT,KD) DZ.
// W generated in KCH-octet LDS chunks, double-buffered: Wgen(c+1) overlaps
// MFMA(c), one barrier per chunk.
// GATE: grid (2,NN); blockIdx.x=0 -> z-half writes z*h into XA (=Xz);
// blockIdx.x=1 -> r-half writes ZRout. !GATE: grid (1,NN); GRU update.
template <int CS, int CIN, int XSPLIT, bool GATE>
__global__ __launch_bounds__(256) void gconv_fused(
    const _Float16* __restrict__ IXh, const _Float16* __restrict__ IXl, int sIX, int oIX,
    const _Float16* __restrict__ IZh, const _Float16* __restrict__ IZl, int sIZ, int oIZ,
    const _Float16* __restrict__ DXh, const _Float16* __restrict__ DXl, int sDX, int oDX,
    const _Float16* __restrict__ DZh, const _Float16* __restrict__ DZl, int sDZ, int oDZ,
    const float* __restrict__ E, const float* __restrict__ wpool,
    const float* __restrict__ bpool, const float* __restrict__ ZRin,
    float* __restrict__ hstate, float* __restrict__ ZRout,
    _Float16* __restrict__ XAh, _Float16* __restrict__ XAl, int csA, int cbA) {
  constexpr int COUT = GATE ? 128 : 64;
  constexpr int KD = 2 * CS;
  constexpr int KP = (KD + 31) & ~31;  // 160 / 256
  constexpr int KO = KP / 8;           // 20 / 32
  constexpr int KCH = 8;               // octets per LDS chunk
  constexpr int NCH = (KO + KCH - 1) / KCH;
  const int n = blockIdx.y;
  const int oc = GATE ? blockIdx.x : 0;
  const int och = oc * 64;
  const int tid = threadIdx.x;
  const int lane = tid & 63, wid = tid >> 6;
  const int wm = (wid & 1) * 32;
  const int wn = (wid >> 1) * 32;
  const int l15 = lane & 15, l4 = lane >> 4;

  __shared__ float sE[EMB];
  __shared__ float sB[64];
  __shared__ _Float16 sWh[2][KCH * 64 * 8];
  __shared__ _Float16 sWl[2][KCH * 64 * 8];

  if (tid < EMB) sE[tid] = E[n * EMB + tid];
  __syncthreads();

  const size_t bIX = (size_t)n * sIX + (size_t)oIX * 512;
  const size_t bIZ = (size_t)n * sIZ + (size_t)oIZ * 512;
  const size_t bDX = (size_t)n * sDX + (size_t)oDX * 512;
  const size_t bDZ = (size_t)n * sDZ + (size_t)oDZ * 512;

  f32x4 acc[2][2] = {};

  // prologue: chunk 0 W + bias
  wgen_chunk<CS, CIN, XSPLIT, COUT>(0, (KO < KCH ? KO : KCH), sE, wpool, och, tid,
                                    sWh[0], sWl[0]);
  if (tid < 64) {
    float bb = 0.0f;
#pragma unroll
    for (int d = 0; d < EMB; ++d) bb += sE[d] * bpool[d * COUT + och + tid];
    sB[tid] = bb;
  }
  __syncthreads();

  for (int c = 0; c < NCH; ++c) {
    const int kob = c * KCH;
    const int kch = (KO - kob < KCH) ? (KO - kob) : KCH;
    // issue next chunk's W-gen first: wpool loads + VALU overlap MFMA(c)
    if (c + 1 < NCH) {
      const int nkob = (c + 1) * KCH;
      const int nkch = (KO - nkob < KCH) ? (KO - nkob) : KCH;
      wgen_chunk<CS, CIN, XSPLIT, COUT>(nkob, nkch, sE, wpool, och, tid,
                                        sWh[(c + 1) & 1], sWl[(c + 1) & 1]);
    }
    const _Float16* cWh = sWh[c & 1];
    const _Float16* cWl = sWl[c & 1];
    // ---- MFMA over k in [kob*8, (kob+kch)*8) ------------------------------
    for (int k0 = kob * 8; k0 < (kob + kch) * 8; k0 += 32) {
      const int kq = k0 + l4 * 8;
      half8 ah[2], al[2];
#pragma unroll
      for (int mt = 0; mt < 2; ++mt) {
        const int b = wm + mt * 16 + l15;
        if (kq < XSPLIT) {
          const size_t o = bIX + (size_t)(kq >> 3) * 512 + (size_t)b * 8;
          ah[mt] = *(const half8*)&IXh[o];
          al[mt] = *(const half8*)&IXl[o];
        } else if (kq < CS) {
          const size_t o = bIZ + (size_t)((kq - XSPLIT) >> 3) * 512 + (size_t)b * 8;
          ah[mt] = *(const half8*)&IZh[o];
          al[mt] = *(const half8*)&IZl[o];
        } else if (kq < CS + XSPLIT) {
          const size_t o = bDX + (size_t)((kq - CS) >> 3) * 512 + (size_t)b * 8;
          ah[mt] = *(const half8*)&DXh[o];
          al[mt] = *(const half8*)&DXl[o];
        } else if (kq < KD) {
          const size_t o =
              bDZ + (size_t)((kq - CS - XSPLIT) >> 3) * 512 + (size_t)b * 8;
          ah[mt] = *(const half8*)&DZh[o];
          al[mt] = *(const half8*)&DZl[o];
        } else {
          ah[mt] = (half8)(_Float16)0.f;
          al[mt] = (half8)(_Float16)0.f;
        }
      }
      const int kol = (kq >> 3) - kob;
#pragma unroll
      for (int nt = 0; nt < 2; ++nt) {
        const int ol = wn + nt * 16 + l15;
        const half8 bh = *(const half8*)&cWh[((size_t)kol * 64 + ol) * 8];
        const half8 bl = *(const half8*)&cWl[((size_t)kol * 64 + ol) * 8];
#pragma unroll
        for (int mt = 0; mt < 2; ++mt) {
          acc[mt][nt] =
              __builtin_amdgcn_mfma_f32_16x16x32_f16(ah[mt], bh, acc[mt][nt], 0, 0, 0);
          acc[mt][nt] =
              __builtin_amdgcn_mfma_f32_16x16x32_f16(ah[mt], bl, acc[mt][nt], 0, 0, 0);
          acc[mt][nt] =
              __builtin_amdgcn_mfma_f32_16x16x32_f16(al[mt], bh, acc[mt][nt], 0, 0, 0);
        }
      }
    }
    if (c + 1 < NCH) __syncthreads();  // Wgen(c+1) visible; MFMA(c) LDS reads done
  }

  // ---- epilogue (octet-major writes) ----
#pragma unroll
  for (int mt = 0; mt < 2; ++mt) {
#pragma unroll
    for (int nt = 0; nt < 2; ++nt) {
      const int ol = wn + nt * 16 + l15;
      const float bias = sB[ol];
#pragma unroll
      for (int r = 0; r < 4; ++r) {
        const int b = wm + mt * 16 + l4 * 4 + r;
        const size_t nb = (size_t)n * 64 + b;
        const float v = acc[mt][nt][r] + bias;
        if constexpr (GATE) {
          const float s = 1.0f / (1.0f + expf(-v));
          if (oc == 0) {  // z half: write z*h compact (cand GEMM input)
            const float zh = s * hstate[nb * 64 + ol];
            const int c2 = cbA + ol;
            size_t ia = (size_t)n * 64 * csA + (size_t)(c2 >> 3) * 512 +
                        (size_t)b * 8 + (c2 & 7);
            split_f16(zh, &XAh[ia], &XAl[ia]);
          } else {  // r half
            ZRout[nb * 64 + ol] = s;
          }
        } else {
          const float hc = tanhf(v);
          const float rr = ZRin[nb * 64 + ol];
          const float hold = hstate[nb * 64 + ol];
          const float hn = rr * hold + (1.0f - rr) * hc;
          hstate[nb * 64 + ol] = hn;
          const int cA = cbA + ol;
          size_t ia = (size_t)n * 64 * csA + (size_t)(cA >> 3) * 512 +
                      (size_t)b * 8 + (cA & 7);
          split_f16(hn, &XAh[ia], &XAl[ia]);
        }
      }
    }
  }
}

// ---------------- output head ------------------------------------------------
__global__ __launch_bounds__(256) void head_kernel(const float* __restrict__ h1,
                                                   const float* __restrict__ cw,
                                                   const float* __restrict__ cb,
                                                   float* __restrict__ out) {
  int i = blockIdx.x * 256 + threadIdx.x;
  if (i >= BB * NN) return;
  int n = i % NN, b = i / NN;
  const float* hrow = h1 + ((size_t)n * 64 + b) * 64;
  float hv[64];
#pragma unroll
  for (int j = 0; j < 64; ++j) hv[j] = hrow[j];
  for (int o = 0; o < 12; ++o) {
    float s = cb[o];
#pragma unroll
    for (int j = 0; j < 64; ++j) s += hv[j] * cw[o * 64 + j];
    out[((size_t)b * 12 + o) * NN + n] = s;
  }
}

__global__ __launch_bounds__(256) void zero_f32(float* __restrict__ p, size_t count) {
  size_t i = (size_t)blockIdx.x * 256 + threadIdx.x;
  if (i < count) p[i] = 0.0f;
}
__global__ __launch_bounds__(256) void zero_u16(unsigned short* __restrict__ p,
                                                size_t count) {
  size_t i = (size_t)blockIdx.x * 256 + threadIdx.x;
  if (i < count) p[i] = 0;
}

extern "C" void kernel_launch(void* const* d_in, const int* in_sizes, int n_in,
                              void* d_out, int out_size, void* d_ws, size_t ws_size,
                              hipStream_t stream) {
  const float* src = (const float*)d_in[0];
  const float* E = (const float*)d_in[1];
  const float* w0g = (const float*)d_in[2];
  const float* b0g = (const float*)d_in[3];
  const float* w0c = (const float*)d_in[4];
  const float* b0c = (const float*)d_in[5];
  const float* w1g = (const float*)d_in[6];
  const float* b1g = (const float*)d_in[7];
  const float* w1c = (const float*)d_in[8];
  const float* b1c = (const float*)d_in[9];
  const float* cw = (const float*)d_in[10];
  const float* cb = (const float*)d_in[11];
  float* out = (float*)d_out;
  float* ws = (float*)d_ws;

  size_t off = 0;
  auto alloc = [&](size_t cnt) {  // cnt in floats
    float* p = ws + off;
    off += (cnt + 63) & ~(size_t)63;
    return p;
  };
  const int LS = TT * 512;  // 6144 (12 t-octets)
  const int L1 = 64 * 128;  // 8192 (16 octets)
  const int LZ = 64 * 64;   // 4096 (8 octets)
  _Float16* Ah = (_Float16*)alloc((size_t)KPAD * KPAD / 2);
  _Float16* Al = (_Float16*)alloc((size_t)KPAD * KPAD / 2);
  // contiguous zero span: Xs, Gx, X1a, Xz, Gl1, Gz (hi/lo pairs)
  _Float16* Xsh = (_Float16*)alloc((size_t)KPAD * LS / 2);
  _Float16* Xsl = (_Float16*)alloc((size_t)KPAD * LS / 2);
  _Float16* Gxh = (_Float16*)alloc((size_t)KPAD * LS / 2);
  _Float16* Gxl = (_Float16*)alloc((size_t)KPAD * LS / 2);
  _Float16* X1ah = (_Float16*)alloc((size_t)KPAD * L1 / 2);
  _Float16* X1al = (_Float16*)alloc((size_t)KPAD * L1 / 2);
  _Float16* Xzh = (_Float16*)alloc((size_t)KPAD * LZ / 2);
  _Float16* Xzl = (_Float16*)alloc((size_t)KPAD * LZ / 2);
  _Float16* Gl1h = (_Float16*)alloc((size_t)KPAD * L1 / 2);
  _Float16* Gl1l = (_Float16*)alloc((size_t)KPAD * L1 / 2);
  _Float16* Gzh = (_Float16*)alloc((size_t)KPAD * LZ / 2);
  _Float16* Gzl = (_Float16*)alloc((size_t)KPAD * LZ / 2);
  float* ZR = alloc((size_t)NN * BB * 64);
  float* h0 = alloc((size_t)NN * BB * 64);
  float* h1 = alloc((size_t)NN * BB * 64);
  if (off * sizeof(float) > ws_size) return;  // ws too small: fail loud (zeros)

  adj_kernel<<<NN, 256, 0, stream>>>(E, Ah, Al);
  {
    size_t cx = (size_t)2 * KPAD * (LS + LS + L1 + LZ + L1 + LZ);  // halves
    size_t chh = (size_t)2 * NN * BB * 64;  // floats (h0,h1 contiguous)
    zero_u16<<<(int)((cx + 255) / 256), 256, 0, stream>>>((unsigned short*)Xsh, cx);
    zero_f32<<<(int)((chh + 255) / 256), 256, 0, stream>>>(h0, chh);
  }
  // Pre-loop: Gx = A @ Xs  (all 12 steps' x diffused, once)
  srcall_kernel<<<(NN * BB * TT + 255) / 256, 256, 0, stream>>>(src, Xsh, Xsl);
  mfma_gemm3<<<dim3(LS / 128, 7), 256, 0, stream>>>(Ah, Al, Xsh, Xsl, Gxh, Gxl, LS);

  const int gx1 = L1 / 128;  // 64
  const int gxz = LZ / 128;  // 32
  for (int t = 0; t < TT; ++t) {
    // ---- layer 0: identity x <- Xs[t], h0 <- X1a octets 0-7;
    //      diffused x <- Gx[t], diffused h0 <- Gl1 octets 0-7 (step t-1) ----
    gconv_fused<72, 65, 8, true><<<dim3(2, NN), 256, 0, stream>>>(
        Xsh, Xsl, LS, t, X1ah, X1al, L1, 0, Gxh, Gxl, LS, t, Gl1h, Gl1l, L1, 0,
        E, w0g, b0g, nullptr, h0, ZR, Xzh, Xzl, 64, 0);
    mfma_gemm3<<<dim3(gxz, 7), 256, 0, stream>>>(Ah, Al, Xzh, Xzl, Gzh, Gzl, LZ);
    gconv_fused<72, 65, 8, false><<<dim3(1, NN), 256, 0, stream>>>(
        Xsh, Xsl, LS, t, Xzh, Xzl, LZ, 0, Gxh, Gxl, LS, t, Gzh, Gzl, LZ, 0,
        E, w0c, b0c, ZR, h0, nullptr, X1ah, X1al, 128, 0);
    // ---- layer 1: identity h0 <- X1a oct 0-7, h1 <- X1a oct 8-15 ----
    mfma_gemm3<<<dim3(gx1, 7), 256, 0, stream>>>(Ah, Al, X1ah, X1al, Gl1h, Gl1l, L1);
    gconv_fused<128, 128, 64, true><<<dim3(2, NN), 256, 0, stream>>>(
        X1ah, X1al, L1, 0, X1ah, X1al, L1, 8, Gl1h, Gl1l, L1, 0, Gl1h, Gl1l, L1, 8,
        E, w1g, b1g, nullptr, h1, ZR, Xzh, Xzl, 64, 0);
    mfma_gemm3<<<dim3(gxz, 7), 256, 0, stream>>>(Ah, Al, Xzh, Xzl, Gzh, Gzl, LZ);
    gconv_fused<128, 128, 64, false><<<dim3(1, NN), 256, 0, stream>>>(
        X1ah, X1al, L1, 0, Xzh, Xzl, LZ, 0, Gl1h, Gl1l, L1, 0, Gzh, Gzl, LZ, 0,
        E, w1c, b1c, ZR, h1, nullptr, X1ah, X1al, 128, 64);
  }
  head_kernel<<<(BB * NN + 255) / 256, 256, 0, stream>>>(h1, cw, cb, out);
}

// Round 13
// 4709.169 us; speedup vs baseline: 1.0867x; 1.0867x over previous
//
#include <hip/hip_runtime.h>
#include <cstddef>

#define NN 883
#define BB 64
#define TT 12
#define EMB 10
#define KPAD 896  // node dim padded to multiple of 128

typedef short short8 __attribute__((ext_vector_type(8)));
typedef _Float16 half8 __attribute__((ext_vector_type(8)));
typedef float f32x4 __attribute__((ext_vector_type(4)));

__device__ __forceinline__ void split_f16(float v, _Float16* hp, _Float16* lp) {
  _Float16 h = (_Float16)v;
  *hp = h;
  *lp = (_Float16)(v - (float)h);
}

// -------- adjacency: A = softmax(relu(E E^T), axis=1), emitted as f16 hi/lo --
__global__ __launch_bounds__(256) void adj_kernel(const float* __restrict__ E,
                                                  _Float16* __restrict__ Ah,
                                                  _Float16* __restrict__ Al) {
  const int n = blockIdx.x;
  const int tid = threadIdx.x;
  __shared__ float sE[EMB];
  __shared__ float sred[256];
  if (tid < EMB) sE[tid] = E[n * EMB + tid];
  __syncthreads();
  float d[4];
  float lmax = 0.0f;
#pragma unroll
  for (int q = 0; q < 4; ++q) {
    int m = tid + q * 256;
    d[q] = 0.0f;
    if (m < NN) {
      float s = 0.0f;
#pragma unroll
      for (int e = 0; e < EMB; ++e) s += sE[e] * E[m * EMB + e];
      d[q] = fmaxf(s, 0.0f);
      lmax = fmaxf(lmax, d[q]);
    }
  }
  sred[tid] = lmax;
  __syncthreads();
  for (int s = 128; s > 0; s >>= 1) {
    if (tid < s) sred[tid] = fmaxf(sred[tid], sred[tid + s]);
    __syncthreads();
  }
  const float mx = sred[0];
  __syncthreads();
  float lsum = 0.0f;
#pragma unroll
  for (int q = 0; q < 4; ++q) {
    int m = tid + q * 256;
    if (m < NN) {
      d[q] = expf(d[q] - mx);
      lsum += d[q];
    }
  }
  sred[tid] = lsum;
  __syncthreads();
  for (int s = 128; s > 0; s >>= 1) {
    if (tid < s) sred[tid] += sred[tid + s];
    __syncthreads();
  }
  const float inv = 1.0f / sred[0];
#pragma unroll
  for (int q = 0; q < 4; ++q) {
    int m = tid + q * 256;
    if (m < KPAD) {
      float v = (m < NN) ? d[q] * inv : 0.0f;
      split_f16(v, &Ah[(size_t)n * KPAD + m], &Al[(size_t)n * KPAD + m]);
    }
  }
}

// -------- 3-term split-f16 MFMA GEMM; output written as split f16 ------------
__global__ __launch_bounds__(256) void mfma_gemm3(const _Float16* __restrict__ Ah,
                                                  const _Float16* __restrict__ Al,
                                                  const _Float16* __restrict__ Xh,
                                                  const _Float16* __restrict__ Xl,
                                                  _Float16* __restrict__ Gh,
                                                  _Float16* __restrict__ Gl, int L) {
  __shared__ _Float16 sA[2][128][40];
  __shared__ _Float16 sX[2][4][128][8];
  const int tid = threadIdx.x;
  const int lane = tid & 63;
  const int wid = tid >> 6;
  const int wm = (wid >> 1) * 64, wn = (wid & 1) * 64;
  const int bm = blockIdx.y * 128;
  const int bl = blockIdx.x * 128;
  const int l15 = lane & 15, l4 = lane >> 4;

  f32x4 acc[4][4] = {};

  const int xlp = (tid & 63) * 2;
  const int xko = tid >> 6;

  for (int k0 = 0; k0 < KPAD; k0 += 32) {
    __syncthreads();
#pragma unroll
    for (int p = 0; p < 2; ++p) {
      int i = tid + p * 256;
      int m = i >> 2, k8 = (i & 3) * 8;
      *(half8*)&sA[0][m][k8] = *(const half8*)&Ah[(size_t)(bm + m) * KPAD + k0 + k8];
      *(half8*)&sA[1][m][k8] = *(const half8*)&Al[(size_t)(bm + m) * KPAD + k0 + k8];
    }
    {
      int gl = bl + xlp;
      int kb = k0 + xko * 8;
#pragma unroll
      for (int buf = 0; buf < 2; ++buf) {
        const _Float16* Xp = buf ? Xl : Xh;
        unsigned int v[8];
#pragma unroll
        for (int j = 0; j < 8; ++j)
          v[j] = *(const unsigned int*)&Xp[(size_t)(kb + j) * L + gl];
        short8 lo, hi;
#pragma unroll
        for (int j = 0; j < 8; ++j) {
          lo[j] = (short)(v[j] & 0xFFFFu);
          hi[j] = (short)(v[j] >> 16);
        }
        *(short8*)&sX[buf][xko][xlp][0] = lo;
        *(short8*)&sX[buf][xko][xlp + 1][0] = hi;
      }
    }
    __syncthreads();
    half8 afh[4], afl[4], bfh[4], bfl[4];
#pragma unroll
    for (int mi = 0; mi < 4; ++mi) {
      afh[mi] = *(half8*)&sA[0][wm + mi * 16 + l15][l4 * 8];
      afl[mi] = *(half8*)&sA[1][wm + mi * 16 + l15][l4 * 8];
    }
#pragma unroll
    for (int ni = 0; ni < 4; ++ni) {
      bfh[ni] = *(half8*)&sX[0][l4][wn + ni * 16 + l15][0];
      bfl[ni] = *(half8*)&sX[1][l4][wn + ni * 16 + l15][0];
    }
#pragma unroll
    for (int mi = 0; mi < 4; ++mi)
#pragma unroll
      for (int ni = 0; ni < 4; ++ni) {
        acc[mi][ni] = __builtin_amdgcn_mfma_f32_16x16x32_f16(afh[mi], bfh[ni],
                                                             acc[mi][ni], 0, 0, 0);
        acc[mi][ni] = __builtin_amdgcn_mfma_f32_16x16x32_f16(afh[mi], bfl[ni],
                                                             acc[mi][ni], 0, 0, 0);
        acc[mi][ni] = __builtin_amdgcn_mfma_f32_16x16x32_f16(afl[mi], bfh[ni],
                                                             acc[mi][ni], 0, 0, 0);
      }
  }
#pragma unroll
  for (int mi = 0; mi < 4; ++mi) {
    int row0 = bm + wm + mi * 16 + l4 * 4;
#pragma unroll
    for (int ni = 0; ni < 4; ++ni) {
      int col = bl + wn + ni * 16 + l15;
#pragma unroll
      for (int r = 0; r < 4; ++r) {
        int row = row0 + r;
        if (row < NN)
          split_f16(acc[mi][ni][r], &Gh[(size_t)row * L + col],
                    &Gl[(size_t)row * L + col]);
      }
    }
  }
}

// -------- build Xs: all 12 steps' x, octet-major [n][t][b][8] (j=0 only) -----
__global__ __launch_bounds__(256) void srcall_kernel(const float* __restrict__ src,
                                                     _Float16* __restrict__ Xsh,
                                                     _Float16* __restrict__ Xsl) {
  int i = blockIdx.x * 256 + threadIdx.x;
  if (i >= NN * BB * TT) return;
  int t = i % TT;
  int nb = i / TT;
  int b = nb & 63, n = nb >> 6;
  float v = src[((size_t)b * TT + t) * NN + n];
  size_t idx = (size_t)n * (TT * 512) + (size_t)t * 512 + (size_t)b * 8;
  split_f16(v, &Xsh[idx], &Xsl[idx]);
}

// -------- fused per-node gconv: monolithic W-gen in LDS + MFMA ---------------
// All operand buffers octet-major per node: [n][ko][b][8], channel = ko*8+j.
// K regions: [0,XSPLIT) IX; [XSPLIT,CS) IZ; [CS,CS+XSPLIT) DX; [CS+XSPLIT,KD) DZ.
// Each region: (hptr, lptr, node-stride in halfs, octet offset).
// W generated once into a full-KO LDS buffer (round-10 structure: one barrier;
// cross-block wave overlap hides the W-gen VALU phase — chunking regressed).
// GATE: grid (2,NN); blockIdx.x=0 -> z-half writes z*h into XA (=Xz);
// blockIdx.x=1 -> r-half writes ZRout. !GATE: grid (1,NN); GRU update.
template <int CS, int CIN, int XSPLIT, bool GATE>
__global__ __launch_bounds__(256) void gconv_fused(
    const _Float16* __restrict__ IXh, const _Float16* __restrict__ IXl, int sIX, int oIX,
    const _Float16* __restrict__ IZh, const _Float16* __restrict__ IZl, int sIZ, int oIZ,
    const _Float16* __restrict__ DXh, const _Float16* __restrict__ DXl, int sDX, int oDX,
    const _Float16* __restrict__ DZh, const _Float16* __restrict__ DZl, int sDZ, int oDZ,
    const float* __restrict__ E, const float* __restrict__ wpool,
    const float* __restrict__ bpool, const float* __restrict__ ZRin,
    float* __restrict__ hstate, float* __restrict__ ZRout,
    _Float16* __restrict__ XAh, _Float16* __restrict__ XAl, int csA, int cbA) {
  constexpr int COUT = GATE ? 128 : 64;
  constexpr int KD = 2 * CS;
  constexpr int KP = (KD + 31) & ~31;  // 160 / 256
  constexpr int KO = KP / 8;           // 20 / 32
  const int n = blockIdx.y;
  const int oc = GATE ? blockIdx.x : 0;
  const int och = oc * 64;
  const int tid = threadIdx.x;
  const int lane = tid & 63, wid = tid >> 6;
  const int wm = (wid & 1) * 32;
  const int wn = (wid >> 1) * 32;
  const int l15 = lane & 15, l4 = lane >> 4;

  __shared__ float sE[EMB];
  __shared__ float sB[64];
  __shared__ _Float16 sWh[KO * 64 * 8];
  __shared__ _Float16 sWl[KO * 64 * 8];

  if (tid < EMB) sE[tid] = E[n * EMB + tid];
  __syncthreads();

  // ---- W gen: octet layout sW[ko][o][8]; remap k -> weight row --------------
  {
    const int o = tid & 63;
    for (int ko = tid >> 6; ko < KO; ko += 4) {
      half8 hv, lv;
#pragma unroll
      for (int j = 0; j < 8; ++j) {
        const int k = ko * 8 + j;
        float w = 0.0f;
        if (k < KD) {
          const int kk = (k >= CS) ? 1 : 0;
          const int kc = k - kk * CS;
          int ii;
          if (CS == CIN) ii = kc;
          else ii = (kc == 0) ? 0 : ((kc >= XSPLIT) ? kc - XSPLIT + 1 : -1);
          if (ii >= 0) {
            const float* wp = wpool + ((size_t)kk * CIN + ii) * COUT + och + o;
#pragma unroll
            for (int d = 0; d < EMB; ++d)
              w += sE[d] * wp[(size_t)d * (2 * CIN * COUT)];
          }
        }
        _Float16 hh = (_Float16)w;
        hv[j] = hh;
        lv[j] = (_Float16)(w - (float)hh);
      }
      *(half8*)&sWh[((size_t)ko * 64 + o) * 8] = hv;
      *(half8*)&sWl[((size_t)ko * 64 + o) * 8] = lv;
    }
    if (tid < 64) {
      float bb = 0.0f;
#pragma unroll
      for (int d = 0; d < EMB; ++d) bb += sE[d] * bpool[d * COUT + och + tid];
      sB[tid] = bb;
    }
  }
  __syncthreads();

  // ---- MFMA: A-fragments coalesced half8 from octet-major global ------------
  const size_t bIX = (size_t)n * sIX + (size_t)oIX * 512;
  const size_t bIZ = (size_t)n * sIZ + (size_t)oIZ * 512;
  const size_t bDX = (size_t)n * sDX + (size_t)oDX * 512;
  const size_t bDZ = (size_t)n * sDZ + (size_t)oDZ * 512;
  f32x4 acc[2][2] = {};
  for (int k0 = 0; k0 < KP; k0 += 32) {
    const int kq = k0 + l4 * 8;
    half8 ah[2], al[2];
#pragma unroll
    for (int mt = 0; mt < 2; ++mt) {
      const int b = wm + mt * 16 + l15;
      if (kq < XSPLIT) {
        const size_t o = bIX + (size_t)(kq >> 3) * 512 + (size_t)b * 8;
        ah[mt] = *(const half8*)&IXh[o];
        al[mt] = *(const half8*)&IXl[o];
      } else if (kq < CS) {
        const size_t o = bIZ + (size_t)((kq - XSPLIT) >> 3) * 512 + (size_t)b * 8;
        ah[mt] = *(const half8*)&IZh[o];
        al[mt] = *(const half8*)&IZl[o];
      } else if (kq < CS + XSPLIT) {
        const size_t o = bDX + (size_t)((kq - CS) >> 3) * 512 + (size_t)b * 8;
        ah[mt] = *(const half8*)&DXh[o];
        al[mt] = *(const half8*)&DXl[o];
      } else if (kq < KD) {
        const size_t o =
            bDZ + (size_t)((kq - CS - XSPLIT) >> 3) * 512 + (size_t)b * 8;
        ah[mt] = *(const half8*)&DZh[o];
        al[mt] = *(const half8*)&DZl[o];
      } else {
        ah[mt] = (half8)(_Float16)0.f;
        al[mt] = (half8)(_Float16)0.f;
      }
    }
    const int koi = kq >> 3;
#pragma unroll
    for (int nt = 0; nt < 2; ++nt) {
      const int ol = wn + nt * 16 + l15;
      const half8 bh = *(const half8*)&sWh[((size_t)koi * 64 + ol) * 8];
      const half8 bl = *(const half8*)&sWl[((size_t)koi * 64 + ol) * 8];
#pragma unroll
      for (int mt = 0; mt < 2; ++mt) {
        acc[mt][nt] =
            __builtin_amdgcn_mfma_f32_16x16x32_f16(ah[mt], bh, acc[mt][nt], 0, 0, 0);
        acc[mt][nt] =
            __builtin_amdgcn_mfma_f32_16x16x32_f16(ah[mt], bl, acc[mt][nt], 0, 0, 0);
        acc[mt][nt] =
            __builtin_amdgcn_mfma_f32_16x16x32_f16(al[mt], bh, acc[mt][nt], 0, 0, 0);
      }
    }
  }

  // ---- epilogue (octet-major writes) ----
#pragma unroll
  for (int mt = 0; mt < 2; ++mt) {
#pragma unroll
    for (int nt = 0; nt < 2; ++nt) {
      const int ol = wn + nt * 16 + l15;
      const float bias = sB[ol];
#pragma unroll
      for (int r = 0; r < 4; ++r) {
        const int b = wm + mt * 16 + l4 * 4 + r;
        const size_t nb = (size_t)n * 64 + b;
        const float v = acc[mt][nt][r] + bias;
        if constexpr (GATE) {
          const float s = 1.0f / (1.0f + expf(-v));
          if (oc == 0) {  // z half: write z*h compact (cand GEMM input)
            const float zh = s * hstate[nb * 64 + ol];
            const int c2 = cbA + ol;
            size_t ia = (size_t)n * 64 * csA + (size_t)(c2 >> 3) * 512 +
                        (size_t)b * 8 + (c2 & 7);
            split_f16(zh, &XAh[ia], &XAl[ia]);
          } else {  // r half
            ZRout[nb * 64 + ol] = s;
          }
        } else {
          const float hc = tanhf(v);
          const float rr = ZRin[nb * 64 + ol];
          const float hold = hstate[nb * 64 + ol];
          const float hn = rr * hold + (1.0f - rr) * hc;
          hstate[nb * 64 + ol] = hn;
          const int cA = cbA + ol;
          size_t ia = (size_t)n * 64 * csA + (size_t)(cA >> 3) * 512 +
                      (size_t)b * 8 + (cA & 7);
          split_f16(hn, &XAh[ia], &XAl[ia]);
        }
      }
    }
  }
}

// ---------------- output head ------------------------------------------------
__global__ __launch_bounds__(256) void head_kernel(const float* __restrict__ h1,
                                                   const float* __restrict__ cw,
                                                   const float* __restrict__ cb,
                                                   float* __restrict__ out) {
  int i = blockIdx.x * 256 + threadIdx.x;
  if (i >= BB * NN) return;
  int n = i % NN, b = i / NN;
  const float* hrow = h1 + ((size_t)n * 64 + b) * 64;
  float hv[64];
#pragma unroll
  for (int j = 0; j < 64; ++j) hv[j] = hrow[j];
  for (int o = 0; o < 12; ++o) {
    float s = cb[o];
#pragma unroll
    for (int j = 0; j < 64; ++j) s += hv[j] * cw[o * 64 + j];
    out[((size_t)b * 12 + o) * NN + n] = s;
  }
}

__global__ __launch_bounds__(256) void zero_f32(float* __restrict__ p, size_t count) {
  size_t i = (size_t)blockIdx.x * 256 + threadIdx.x;
  if (i < count) p[i] = 0.0f;
}
__global__ __launch_bounds__(256) void zero_u16(unsigned short* __restrict__ p,
                                                size_t count) {
  size_t i = (size_t)blockIdx.x * 256 + threadIdx.x;
  if (i < count) p[i] = 0;
}

extern "C" void kernel_launch(void* const* d_in, const int* in_sizes, int n_in,
                              void* d_out, int out_size, void* d_ws, size_t ws_size,
                              hipStream_t stream) {
  const float* src = (const float*)d_in[0];
  const float* E = (const float*)d_in[1];
  const float* w0g = (const float*)d_in[2];
  const float* b0g = (const float*)d_in[3];
  const float* w0c = (const float*)d_in[4];
  const float* b0c = (const float*)d_in[5];
  const float* w1g = (const float*)d_in[6];
  const float* b1g = (const float*)d_in[7];
  const float* w1c = (const float*)d_in[8];
  const float* b1c = (const float*)d_in[9];
  const float* cw = (const float*)d_in[10];
  const float* cb = (const float*)d_in[11];
  float* out = (float*)d_out;
  float* ws = (float*)d_ws;

  size_t off = 0;
  auto alloc = [&](size_t cnt) {  // cnt in floats
    float* p = ws + off;
    off += (cnt + 63) & ~(size_t)63;
    return p;
  };
  const int LS = TT * 512;  // 6144 (12 t-octets)
  const int L1 = 64 * 128;  // 8192 (16 octets)
  const int LZ = 64 * 64;   // 4096 (8 octets)
  _Float16* Ah = (_Float16*)alloc((size_t)KPAD * KPAD / 2);
  _Float16* Al = (_Float16*)alloc((size_t)KPAD * KPAD / 2);
  // contiguous zero span: Xs, Gx, X1a, Xz, Gl1, Gz (hi/lo pairs)
  _Float16* Xsh = (_Float16*)alloc((size_t)KPAD * LS / 2);
  _Float16* Xsl = (_Float16*)alloc((size_t)KPAD * LS / 2);
  _Float16* Gxh = (_Float16*)alloc((size_t)KPAD * LS / 2);
  _Float16* Gxl = (_Float16*)alloc((size_t)KPAD * LS / 2);
  _Float16* X1ah = (_Float16*)alloc((size_t)KPAD * L1 / 2);
  _Float16* X1al = (_Float16*)alloc((size_t)KPAD * L1 / 2);
  _Float16* Xzh = (_Float16*)alloc((size_t)KPAD * LZ / 2);
  _Float16* Xzl = (_Float16*)alloc((size_t)KPAD * LZ / 2);
  _Float16* Gl1h = (_Float16*)alloc((size_t)KPAD * L1 / 2);
  _Float16* Gl1l = (_Float16*)alloc((size_t)KPAD * L1 / 2);
  _Float16* Gzh = (_Float16*)alloc((size_t)KPAD * LZ / 2);
  _Float16* Gzl = (_Float16*)alloc((size_t)KPAD * LZ / 2);
  float* ZR = alloc((size_t)NN * BB * 64);
  float* h0 = alloc((size_t)NN * BB * 64);
  float* h1 = alloc((size_t)NN * BB * 64);
  if (off * sizeof(float) > ws_size) return;  // ws too small: fail loud (zeros)

  adj_kernel<<<NN, 256, 0, stream>>>(E, Ah, Al);
  {
    size_t cx = (size_t)2 * KPAD * (LS + LS + L1 + LZ + L1 + LZ);  // halves
    size_t chh = (size_t)2 * NN * BB * 64;  // floats (h0,h1 contiguous)
    zero_u16<<<(int)((cx + 255) / 256), 256, 0, stream>>>((unsigned short*)Xsh, cx);
    zero_f32<<<(int)((chh + 255) / 256), 256, 0, stream>>>(h0, chh);
  }
  // Pre-loop: Gx = A @ Xs  (all 12 steps' x diffused, once)
  srcall_kernel<<<(NN * BB * TT + 255) / 256, 256, 0, stream>>>(src, Xsh, Xsl);
  mfma_gemm3<<<dim3(LS / 128, 7), 256, 0, stream>>>(Ah, Al, Xsh, Xsl, Gxh, Gxl, LS);

  const int gx1 = L1 / 128;  // 64
  const int gxz = LZ / 128;  // 32
  for (int t = 0; t < TT; ++t) {
    // ---- layer 0: identity x <- Xs[t], h0 <- X1a octets 0-7;
    //      diffused x <- Gx[t], diffused h0 <- Gl1 octets 0-7 (step t-1) ----
    gconv_fused<72, 65, 8, true><<<dim3(2, NN), 256, 0, stream>>>(
        Xsh, Xsl, LS, t, X1ah, X1al, L1, 0, Gxh, Gxl, LS, t, Gl1h, Gl1l, L1, 0,
        E, w0g, b0g, nullptr, h0, ZR, Xzh, Xzl, 64, 0);
    mfma_gemm3<<<dim3(gxz, 7), 256, 0, stream>>>(Ah, Al, Xzh, Xzl, Gzh, Gzl, LZ);
    gconv_fused<72, 65, 8, false><<<dim3(1, NN), 256, 0, stream>>>(
        Xsh, Xsl, LS, t, Xzh, Xzl, LZ, 0, Gxh, Gxl, LS, t, Gzh, Gzl, LZ, 0,
        E, w0c, b0c, ZR, h0, nullptr, X1ah, X1al, 128, 0);
    // ---- layer 1: identity h0 <- X1a oct 0-7, h1 <- X1a oct 8-15 ----
    mfma_gemm3<<<dim3(gx1, 7), 256, 0, stream>>>(Ah, Al, X1ah, X1al, Gl1h, Gl1l, L1);
    gconv_fused<128, 128, 64, true><<<dim3(2, NN), 256, 0, stream>>>(
        X1ah, X1al, L1, 0, X1ah, X1al, L1, 8, Gl1h, Gl1l, L1, 0, Gl1h, Gl1l, L1, 8,
        E, w1g, b1g, nullptr, h1, ZR, Xzh, Xzl, 64, 0);
    mfma_gemm3<<<dim3(gxz, 7), 256, 0, stream>>>(Ah, Al, Xzh, Xzl, Gzh, Gzl, LZ);
    gconv_fused<128, 128, 64, false><<<dim3(1, NN), 256, 0, stream>>>(
        X1ah, X1al, L1, 0, Xzh, Xzl, LZ, 0, Gl1h, Gl1l, L1, 0, Gzh, Gzl, LZ, 0,
        E, w1c, b1c, ZR, h1, nullptr, X1ah, X1al, 128, 64);
  }
  head_kernel<<<(BB * NN + 255) / 256, 256, 0, stream>>>(h1, cw, cb, out);
}

// Round 14
// 4190.601 us; speedup vs baseline: 1.2211x; 1.1237x over previous
//
#include <hip/hip_runtime.h>
#include <cstddef>

#define NN 883
#define BB 64
#define TT 12
#define EMB 10
#define KPAD 896  // node dim padded to multiple of 128

typedef short short8 __attribute__((ext_vector_type(8)));
typedef _Float16 half8 __attribute__((ext_vector_type(8)));
typedef float f32x4 __attribute__((ext_vector_type(4)));

__device__ __forceinline__ void split_f16(float v, _Float16* hp, _Float16* lp) {
  _Float16 h = (_Float16)v;
  *hp = h;
  *lp = (_Float16)(v - (float)h);
}

// -------- adjacency: A = softmax(relu(E E^T), axis=1), emitted as f16 hi/lo --
__global__ __launch_bounds__(256) void adj_kernel(const float* __restrict__ E,
                                                  _Float16* __restrict__ Ah,
                                                  _Float16* __restrict__ Al) {
  const int n = blockIdx.x;
  const int tid = threadIdx.x;
  __shared__ float sE[EMB];
  __shared__ float sred[256];
  if (tid < EMB) sE[tid] = E[n * EMB + tid];
  __syncthreads();
  float d[4];
  float lmax = 0.0f;
#pragma unroll
  for (int q = 0; q < 4; ++q) {
    int m = tid + q * 256;
    d[q] = 0.0f;
    if (m < NN) {
      float s = 0.0f;
#pragma unroll
      for (int e = 0; e < EMB; ++e) s += sE[e] * E[m * EMB + e];
      d[q] = fmaxf(s, 0.0f);
      lmax = fmaxf(lmax, d[q]);
    }
  }
  sred[tid] = lmax;
  __syncthreads();
  for (int s = 128; s > 0; s >>= 1) {
    if (tid < s) sred[tid] = fmaxf(sred[tid], sred[tid + s]);
    __syncthreads();
  }
  const float mx = sred[0];
  __syncthreads();
  float lsum = 0.0f;
#pragma unroll
  for (int q = 0; q < 4; ++q) {
    int m = tid + q * 256;
    if (m < NN) {
      d[q] = expf(d[q] - mx);
      lsum += d[q];
    }
  }
  sred[tid] = lsum;
  __syncthreads();
  for (int s = 128; s > 0; s >>= 1) {
    if (tid < s) sred[tid] += sred[tid + s];
    __syncthreads();
  }
  const float inv = 1.0f / sred[0];
#pragma unroll
  for (int q = 0; q < 4; ++q) {
    int m = tid + q * 256;
    if (m < KPAD) {
      float v = (m < NN) ? d[q] * inv : 0.0f;
      split_f16(v, &Ah[(size_t)n * KPAD + m], &Al[(size_t)n * KPAD + m]);
    }
  }
}

// -------- 3-term split-f16 MFMA GEMM; output written as split f16 ------------
__global__ __launch_bounds__(256) void mfma_gemm3(const _Float16* __restrict__ Ah,
                                                  const _Float16* __restrict__ Al,
                                                  const _Float16* __restrict__ Xh,
                                                  const _Float16* __restrict__ Xl,
                                                  _Float16* __restrict__ Gh,
                                                  _Float16* __restrict__ Gl, int L) {
  __shared__ _Float16 sA[2][128][40];
  __shared__ _Float16 sX[2][4][128][8];
  const int tid = threadIdx.x;
  const int lane = tid & 63;
  const int wid = tid >> 6;
  const int wm = (wid >> 1) * 64, wn = (wid & 1) * 64;
  const int bm = blockIdx.y * 128;
  const int bl = blockIdx.x * 128;
  const int l15 = lane & 15, l4 = lane >> 4;

  f32x4 acc[4][4] = {};

  const int xlp = (tid & 63) * 2;
  const int xko = tid >> 6;

  for (int k0 = 0; k0 < KPAD; k0 += 32) {
    __syncthreads();
#pragma unroll
    for (int p = 0; p < 2; ++p) {
      int i = tid + p * 256;
      int m = i >> 2, k8 = (i & 3) * 8;
      *(half8*)&sA[0][m][k8] = *(const half8*)&Ah[(size_t)(bm + m) * KPAD + k0 + k8];
      *(half8*)&sA[1][m][k8] = *(const half8*)&Al[(size_t)(bm + m) * KPAD + k0 + k8];
    }
    {
      int gl = bl + xlp;
      int kb = k0 + xko * 8;
#pragma unroll
      for (int buf = 0; buf < 2; ++buf) {
        const _Float16* Xp = buf ? Xl : Xh;
        unsigned int v[8];
#pragma unroll
        for (int j = 0; j < 8; ++j)
          v[j] = *(const unsigned int*)&Xp[(size_t)(kb + j) * L + gl];
        short8 lo, hi;
#pragma unroll
        for (int j = 0; j < 8; ++j) {
          lo[j] = (short)(v[j] & 0xFFFFu);
          hi[j] = (short)(v[j] >> 16);
        }
        *(short8*)&sX[buf][xko][xlp][0] = lo;
        *(short8*)&sX[buf][xko][xlp + 1][0] = hi;
      }
    }
    __syncthreads();
    half8 afh[4], afl[4], bfh[4], bfl[4];
#pragma unroll
    for (int mi = 0; mi < 4; ++mi) {
      afh[mi] = *(half8*)&sA[0][wm + mi * 16 + l15][l4 * 8];
      afl[mi] = *(half8*)&sA[1][wm + mi * 16 + l15][l4 * 8];
    }
#pragma unroll
    for (int ni = 0; ni < 4; ++ni) {
      bfh[ni] = *(half8*)&sX[0][l4][wn + ni * 16 + l15][0];
      bfl[ni] = *(half8*)&sX[1][l4][wn + ni * 16 + l15][0];
    }
#pragma unroll
    for (int mi = 0; mi < 4; ++mi)
#pragma unroll
      for (int ni = 0; ni < 4; ++ni) {
        acc[mi][ni] = __builtin_amdgcn_mfma_f32_16x16x32_f16(afh[mi], bfh[ni],
                                                             acc[mi][ni], 0, 0, 0);
        acc[mi][ni] = __builtin_amdgcn_mfma_f32_16x16x32_f16(afh[mi], bfl[ni],
                                                             acc[mi][ni], 0, 0, 0);
        acc[mi][ni] = __builtin_amdgcn_mfma_f32_16x16x32_f16(afl[mi], bfh[ni],
                                                             acc[mi][ni], 0, 0, 0);
      }
  }
#pragma unroll
  for (int mi = 0; mi < 4; ++mi) {
    int row0 = bm + wm + mi * 16 + l4 * 4;
#pragma unroll
    for (int ni = 0; ni < 4; ++ni) {
      int col = bl + wn + ni * 16 + l15;
#pragma unroll
      for (int r = 0; r < 4; ++r) {
        int row = row0 + r;
        if (row < NN)
          split_f16(acc[mi][ni][r], &Gh[(size_t)row * L + col],
                    &Gl[(size_t)row * L + col]);
      }
    }
  }
}

// -------- build Xs: all 12 steps' x, octet-major [n][t][b][8] (j=0 only) -----
__global__ __launch_bounds__(256) void srcall_kernel(const float* __restrict__ src,
                                                     _Float16* __restrict__ Xsh,
                                                     _Float16* __restrict__ Xsl) {
  int i = blockIdx.x * 256 + threadIdx.x;
  if (i >= NN * BB * TT) return;
  int t = i % TT;
  int nb = i / TT;
  int b = nb & 63, n = nb >> 6;
  float v = src[((size_t)b * TT + t) * NN + n];
  size_t idx = (size_t)n * (TT * 512) + (size_t)t * 512 + (size_t)b * 8;
  split_f16(v, &Xsh[idx], &Xsl[idx]);
}

// -------- fused per-node gconv: monolithic W-gen in LDS + MFMA ---------------
// All operand buffers octet-major per node: [n][ko][b][8], channel = ko*8+j.
// K regions: [0,XSPLIT) IX; [XSPLIT,CS) IZ; [CS,CS+XSPLIT) DX; [CS+XSPLIT,KD) DZ.
// Each region: (hptr, lptr, node-stride in halfs, octet offset).
// W LDS holds only KD/8 octets (k >= KD is structurally zero); for layer0 this
// trims 41.5 -> 37.4 KB crossing the 40 KB threshold: 3 -> 4 blocks/CU.
// GATE: grid (2,NN); blockIdx.x=0 -> z-half writes z*h into XA (=Xz);
// blockIdx.x=1 -> r-half writes ZRout. !GATE: grid (1,NN); GRU update.
template <int CS, int CIN, int XSPLIT, bool GATE>
__global__ __launch_bounds__(256) void gconv_fused(
    const _Float16* __restrict__ IXh, const _Float16* __restrict__ IXl, int sIX, int oIX,
    const _Float16* __restrict__ IZh, const _Float16* __restrict__ IZl, int sIZ, int oIZ,
    const _Float16* __restrict__ DXh, const _Float16* __restrict__ DXl, int sDX, int oDX,
    const _Float16* __restrict__ DZh, const _Float16* __restrict__ DZl, int sDZ, int oDZ,
    const float* __restrict__ E, const float* __restrict__ wpool,
    const float* __restrict__ bpool, const float* __restrict__ ZRin,
    float* __restrict__ hstate, float* __restrict__ ZRout,
    _Float16* __restrict__ XAh, _Float16* __restrict__ XAl, int csA, int cbA) {
  constexpr int COUT = GATE ? 128 : 64;
  constexpr int KD = 2 * CS;
  constexpr int KP = (KD + 31) & ~31;  // 160 / 256 (MFMA loop extent)
  constexpr int KOW = KD / 8;          // 18 / 32 (W octets actually stored)
  const int n = blockIdx.y;
  const int oc = GATE ? blockIdx.x : 0;
  const int och = oc * 64;
  const int tid = threadIdx.x;
  const int lane = tid & 63, wid = tid >> 6;
  const int wm = (wid & 1) * 32;
  const int wn = (wid >> 1) * 32;
  const int l15 = lane & 15, l4 = lane >> 4;

  __shared__ float sE[EMB];
  __shared__ float sB[64];
  __shared__ _Float16 sWh[KOW * 64 * 8];
  __shared__ _Float16 sWl[KOW * 64 * 8];

  if (tid < EMB) sE[tid] = E[n * EMB + tid];
  __syncthreads();

  // ---- W gen: octet layout sW[ko][o][8]; remap k -> weight row --------------
  {
    const int o = tid & 63;
    for (int ko = tid >> 6; ko < KOW; ko += 4) {
      half8 hv, lv;
#pragma unroll
      for (int j = 0; j < 8; ++j) {
        const int k = ko * 8 + j;
        const int kk = (k >= CS) ? 1 : 0;
        const int kc = k - kk * CS;
        int ii;
        if (CS == CIN) ii = kc;
        else ii = (kc == 0) ? 0 : ((kc >= XSPLIT) ? kc - XSPLIT + 1 : -1);
        float w = 0.0f;
        if (ii >= 0) {
          const float* wp = wpool + ((size_t)kk * CIN + ii) * COUT + och + o;
#pragma unroll
          for (int d = 0; d < EMB; ++d)
            w += sE[d] * wp[(size_t)d * (2 * CIN * COUT)];
        }
        _Float16 hh = (_Float16)w;
        hv[j] = hh;
        lv[j] = (_Float16)(w - (float)hh);
      }
      *(half8*)&sWh[((size_t)ko * 64 + o) * 8] = hv;
      *(half8*)&sWl[((size_t)ko * 64 + o) * 8] = lv;
    }
    if (tid < 64) {
      float bb = 0.0f;
#pragma unroll
      for (int d = 0; d < EMB; ++d) bb += sE[d] * bpool[d * COUT + och + tid];
      sB[tid] = bb;
    }
  }
  __syncthreads();

  // ---- MFMA: A-fragments coalesced half8 from octet-major global ------------
  const size_t bIX = (size_t)n * sIX + (size_t)oIX * 512;
  const size_t bIZ = (size_t)n * sIZ + (size_t)oIZ * 512;
  const size_t bDX = (size_t)n * sDX + (size_t)oDX * 512;
  const size_t bDZ = (size_t)n * sDZ + (size_t)oDZ * 512;
  f32x4 acc[2][2] = {};
  for (int k0 = 0; k0 < KP; k0 += 32) {
    const int kq = k0 + l4 * 8;
    half8 ah[2], al[2];
#pragma unroll
    for (int mt = 0; mt < 2; ++mt) {
      const int b = wm + mt * 16 + l15;
      if (kq < XSPLIT) {
        const size_t o = bIX + (size_t)(kq >> 3) * 512 + (size_t)b * 8;
        ah[mt] = *(const half8*)&IXh[o];
        al[mt] = *(const half8*)&IXl[o];
      } else if (kq < CS) {
        const size_t o = bIZ + (size_t)((kq - XSPLIT) >> 3) * 512 + (size_t)b * 8;
        ah[mt] = *(const half8*)&IZh[o];
        al[mt] = *(const half8*)&IZl[o];
      } else if (kq < CS + XSPLIT) {
        const size_t o = bDX + (size_t)((kq - CS) >> 3) * 512 + (size_t)b * 8;
        ah[mt] = *(const half8*)&DXh[o];
        al[mt] = *(const half8*)&DXl[o];
      } else if (kq < KD) {
        const size_t o =
            bDZ + (size_t)((kq - CS - XSPLIT) >> 3) * 512 + (size_t)b * 8;
        ah[mt] = *(const half8*)&DZh[o];
        al[mt] = *(const half8*)&DZl[o];
      } else {
        ah[mt] = (half8)(_Float16)0.f;
        al[mt] = (half8)(_Float16)0.f;
      }
    }
    const int koi = kq >> 3;
#pragma unroll
    for (int nt = 0; nt < 2; ++nt) {
      const int ol = wn + nt * 16 + l15;
      half8 bh, bl;
      if constexpr (KP == KD) {
        bh = *(const half8*)&sWh[((size_t)koi * 64 + ol) * 8];
        bl = *(const half8*)&sWl[((size_t)koi * 64 + ol) * 8];
      } else {
        if (kq < KD) {
          bh = *(const half8*)&sWh[((size_t)koi * 64 + ol) * 8];
          bl = *(const half8*)&sWl[((size_t)koi * 64 + ol) * 8];
        } else {
          bh = (half8)(_Float16)0.f;
          bl = (half8)(_Float16)0.f;
        }
      }
#pragma unroll
      for (int mt = 0; mt < 2; ++mt) {
        acc[mt][nt] =
            __builtin_amdgcn_mfma_f32_16x16x32_f16(ah[mt], bh, acc[mt][nt], 0, 0, 0);
        acc[mt][nt] =
            __builtin_amdgcn_mfma_f32_16x16x32_f16(ah[mt], bl, acc[mt][nt], 0, 0, 0);
        acc[mt][nt] =
            __builtin_amdgcn_mfma_f32_16x16x32_f16(al[mt], bh, acc[mt][nt], 0, 0, 0);
      }
    }
  }

  // ---- epilogue (octet-major writes) ----
#pragma unroll
  for (int mt = 0; mt < 2; ++mt) {
#pragma unroll
    for (int nt = 0; nt < 2; ++nt) {
      const int ol = wn + nt * 16 + l15;
      const float bias = sB[ol];
#pragma unroll
      for (int r = 0; r < 4; ++r) {
        const int b = wm + mt * 16 + l4 * 4 + r;
        const size_t nb = (size_t)n * 64 + b;
        const float v = acc[mt][nt][r] + bias;
        if constexpr (GATE) {
          const float s = 1.0f / (1.0f + expf(-v));
          if (oc == 0) {  // z half: write z*h compact (cand GEMM input)
            const float zh = s * hstate[nb * 64 + ol];
            const int c2 = cbA + ol;
            size_t ia = (size_t)n * 64 * csA + (size_t)(c2 >> 3) * 512 +
                        (size_t)b * 8 + (c2 & 7);
            split_f16(zh, &XAh[ia], &XAl[ia]);
          } else {  // r half
            ZRout[nb * 64 + ol] = s;
          }
        } else {
          const float hc = tanhf(v);
          const float rr = ZRin[nb * 64 + ol];
          const float hold = hstate[nb * 64 + ol];
          const float hn = rr * hold + (1.0f - rr) * hc;
          hstate[nb * 64 + ol] = hn;
          const int cA = cbA + ol;
          size_t ia = (size_t)n * 64 * csA + (size_t)(cA >> 3) * 512 +
                      (size_t)b * 8 + (cA & 7);
          split_f16(hn, &XAh[ia], &XAl[ia]);
        }
      }
    }
  }
}

// ---------------- output head ------------------------------------------------
__global__ __launch_bounds__(256) void head_kernel(const float* __restrict__ h1,
                                                   const float* __restrict__ cw,
                                                   const float* __restrict__ cb,
                                                   float* __restrict__ out) {
  int i = blockIdx.x * 256 + threadIdx.x;
  if (i >= BB * NN) return;
  int n = i % NN, b = i / NN;
  const float* hrow = h1 + ((size_t)n * 64 + b) * 64;
  float hv[64];
#pragma unroll
  for (int j = 0; j < 64; ++j) hv[j] = hrow[j];
  for (int o = 0; o < 12; ++o) {
    float s = cb[o];
#pragma unroll
    for (int j = 0; j < 64; ++j) s += hv[j] * cw[o * 64 + j];
    out[((size_t)b * 12 + o) * NN + n] = s;
  }
}

__global__ __launch_bounds__(256) void zero_f32(float* __restrict__ p, size_t count) {
  size_t i = (size_t)blockIdx.x * 256 + threadIdx.x;
  if (i < count) p[i] = 0.0f;
}
__global__ __launch_bounds__(256) void zero_u16(unsigned short* __restrict__ p,
                                                size_t count) {
  size_t i = (size_t)blockIdx.x * 256 + threadIdx.x;
  if (i < count) p[i] = 0;
}

extern "C" void kernel_launch(void* const* d_in, const int* in_sizes, int n_in,
                              void* d_out, int out_size, void* d_ws, size_t ws_size,
                              hipStream_t stream) {
  const float* src = (const float*)d_in[0];
  const float* E = (const float*)d_in[1];
  const float* w0g = (const float*)d_in[2];
  const float* b0g = (const float*)d_in[3];
  const float* w0c = (const float*)d_in[4];
  const float* b0c = (const float*)d_in[5];
  const float* w1g = (const float*)d_in[6];
  const float* b1g = (const float*)d_in[7];
  const float* w1c = (const float*)d_in[8];
  const float* b1c = (const float*)d_in[9];
  const float* cw = (const float*)d_in[10];
  const float* cb = (const float*)d_in[11];
  float* out = (float*)d_out;
  float* ws = (float*)d_ws;

  size_t off = 0;
  auto alloc = [&](size_t cnt) {  // cnt in floats
    float* p = ws + off;
    off += (cnt + 63) & ~(size_t)63;
    return p;
  };
  const int LS = TT * 512;  // 6144 (12 t-octets)
  const int L1 = 64 * 128;  // 8192 (16 octets)
  const int LZ = 64 * 64;   // 4096 (8 octets)
  _Float16* Ah = (_Float16*)alloc((size_t)KPAD * KPAD / 2);
  _Float16* Al = (_Float16*)alloc((size_t)KPAD * KPAD / 2);
  // contiguous zero span: Xs, Gx, X1a, Xz, Gl1, Gz (hi/lo pairs)
  _Float16* Xsh = (_Float16*)alloc((size_t)KPAD * LS / 2);
  _Float16* Xsl = (_Float16*)alloc((size_t)KPAD * LS / 2);
  _Float16* Gxh = (_Float16*)alloc((size_t)KPAD * LS / 2);
  _Float16* Gxl = (_Float16*)alloc((size_t)KPAD * LS / 2);
  _Float16* X1ah = (_Float16*)alloc((size_t)KPAD * L1 / 2);
  _Float16* X1al = (_Float16*)alloc((size_t)KPAD * L1 / 2);
  _Float16* Xzh = (_Float16*)alloc((size_t)KPAD * LZ / 2);
  _Float16* Xzl = (_Float16*)alloc((size_t)KPAD * LZ / 2);
  _Float16* Gl1h = (_Float16*)alloc((size_t)KPAD * L1 / 2);
  _Float16* Gl1l = (_Float16*)alloc((size_t)KPAD * L1 / 2);
  _Float16* Gzh = (_Float16*)alloc((size_t)KPAD * LZ / 2);
  _Float16* Gzl = (_Float16*)alloc((size_t)KPAD * LZ / 2);
  float* ZR = alloc((size_t)NN * BB * 64);
  float* h0 = alloc((size_t)NN * BB * 64);
  float* h1 = alloc((size_t)NN * BB * 64);
  if (off * sizeof(float) > ws_size) return;  // ws too small: fail loud (zeros)

  adj_kernel<<<NN, 256, 0, stream>>>(E, Ah, Al);
  {
    size_t cx = (size_t)2 * KPAD * (LS + LS + L1 + LZ + L1 + LZ);  // halves
    size_t chh = (size_t)2 * NN * BB * 64;  // floats (h0,h1 contiguous)
    zero_u16<<<(int)((cx + 255) / 256), 256, 0, stream>>>((unsigned short*)Xsh, cx);
    zero_f32<<<(int)((chh + 255) / 256), 256, 0, stream>>>(h0, chh);
  }
  // Pre-loop: Gx = A @ Xs  (all 12 steps' x diffused, once)
  srcall_kernel<<<(NN * BB * TT + 255) / 256, 256, 0, stream>>>(src, Xsh, Xsl);
  mfma_gemm3<<<dim3(LS / 128, 7), 256, 0, stream>>>(Ah, Al, Xsh, Xsl, Gxh, Gxl, LS);

  const int gx1 = L1 / 128;  // 64
  const int gxz = LZ / 128;  // 32
  for (int t = 0; t < TT; ++t) {
    // ---- layer 0: identity x <- Xs[t], h0 <- X1a octets 0-7;
    //      diffused x <- Gx[t], diffused h0 <- Gl1 octets 0-7 (step t-1) ----
    gconv_fused<72, 65, 8, true><<<dim3(2, NN), 256, 0, stream>>>(
        Xsh, Xsl, LS, t, X1ah, X1al, L1, 0, Gxh, Gxl, LS, t, Gl1h, Gl1l, L1, 0,
        E, w0g, b0g, nullptr, h0, ZR, Xzh, Xzl, 64, 0);
    mfma_gemm3<<<dim3(gxz, 7), 256, 0, stream>>>(Ah, Al, Xzh, Xzl, Gzh, Gzl, LZ);
    gconv_fused<72, 65, 8, false><<<dim3(1, NN), 256, 0, stream>>>(
        Xsh, Xsl, LS, t, Xzh, Xzl, LZ, 0, Gxh, Gxl, LS, t, Gzh, Gzl, LZ, 0,
        E, w0c, b0c, ZR, h0, nullptr, X1ah, X1al, 128, 0);
    // ---- layer 1: identity h0 <- X1a oct 0-7, h1 <- X1a oct 8-15 ----
    mfma_gemm3<<<dim3(gx1, 7), 256, 0, stream>>>(Ah, Al, X1ah, X1al, Gl1h, Gl1l, L1);
    gconv_fused<128, 128, 64, true><<<dim3(2, NN), 256, 0, stream>>>(
        X1ah, X1al, L1, 0, X1ah, X1al, L1, 8, Gl1h, Gl1l, L1, 0, Gl1h, Gl1l, L1, 8,
        E, w1g, b1g, nullptr, h1, ZR, Xzh, Xzl, 64, 0);
    mfma_gemm3<<<dim3(gxz, 7), 256, 0, stream>>>(Ah, Al, Xzh, Xzl, Gzh, Gzl, LZ);
    gconv_fused<128, 128, 64, false><<<dim3(1, NN), 256, 0, stream>>>(
        X1ah, X1al, L1, 0, Xzh, Xzl, LZ, 0, Gl1h, Gl1l, L1, 0, Gzh, Gzl, LZ, 0,
        E, w1c, b1c, ZR, h1, nullptr, X1ah, X1al, 128, 64);
  }
  head_kernel<<<(BB * NN + 255) / 256, 256, 0, stream>>>(h1, cw, cb, out);
}

// Round 15
// 4164.370 us; speedup vs baseline: 1.2288x; 1.0063x over previous
//
#include <hip/hip_runtime.h>
#include <cstddef>

#define NN 883
#define BB 64
#define TT 12
#define EMB 10
#define KPAD 896  // node dim padded to multiple of 128

typedef short short8 __attribute__((ext_vector_type(8)));
typedef _Float16 half8 __attribute__((ext_vector_type(8)));
typedef float f32x4 __attribute__((ext_vector_type(4)));

__device__ __forceinline__ void split_f16(float v, _Float16* hp, _Float16* lp) {
  _Float16 h = (_Float16)v;
  *hp = h;
  *lp = (_Float16)(v - (float)h);
}

// -------- adjacency: A = softmax(relu(E E^T), axis=1), emitted as f16 hi/lo --
__global__ __launch_bounds__(256) void adj_kernel(const float* __restrict__ E,
                                                  _Float16* __restrict__ Ah,
                                                  _Float16* __restrict__ Al) {
  const int n = blockIdx.x;
  const int tid = threadIdx.x;
  __shared__ float sE[EMB];
  __shared__ float sred[256];
  if (tid < EMB) sE[tid] = E[n * EMB + tid];
  __syncthreads();
  float d[4];
  float lmax = 0.0f;
#pragma unroll
  for (int q = 0; q < 4; ++q) {
    int m = tid + q * 256;
    d[q] = 0.0f;
    if (m < NN) {
      float s = 0.0f;
#pragma unroll
      for (int e = 0; e < EMB; ++e) s += sE[e] * E[m * EMB + e];
      d[q] = fmaxf(s, 0.0f);
      lmax = fmaxf(lmax, d[q]);
    }
  }
  sred[tid] = lmax;
  __syncthreads();
  for (int s = 128; s > 0; s >>= 1) {
    if (tid < s) sred[tid] = fmaxf(sred[tid], sred[tid + s]);
    __syncthreads();
  }
  const float mx = sred[0];
  __syncthreads();
  float lsum = 0.0f;
#pragma unroll
  for (int q = 0; q < 4; ++q) {
    int m = tid + q * 256;
    if (m < NN) {
      d[q] = expf(d[q] - mx);
      lsum += d[q];
    }
  }
  sred[tid] = lsum;
  __syncthreads();
  for (int s = 128; s > 0; s >>= 1) {
    if (tid < s) sred[tid] += sred[tid + s];
    __syncthreads();
  }
  const float inv = 1.0f / sred[0];
#pragma unroll
  for (int q = 0; q < 4; ++q) {
    int m = tid + q * 256;
    if (m < KPAD) {
      float v = (m < NN) ? d[q] * inv : 0.0f;
      split_f16(v, &Ah[(size_t)n * KPAD + m], &Al[(size_t)n * KPAD + m]);
    }
  }
}

// -------- 3-term split-f16 MFMA GEMM; output written as split f16 ------------
__global__ __launch_bounds__(256) void mfma_gemm3(const _Float16* __restrict__ Ah,
                                                  const _Float16* __restrict__ Al,
                                                  const _Float16* __restrict__ Xh,
                                                  const _Float16* __restrict__ Xl,
                                                  _Float16* __restrict__ Gh,
                                                  _Float16* __restrict__ Gl, int L) {
  __shared__ _Float16 sA[2][128][40];
  __shared__ _Float16 sX[2][4][128][8];
  const int tid = threadIdx.x;
  const int lane = tid & 63;
  const int wid = tid >> 6;
  const int wm = (wid >> 1) * 64, wn = (wid & 1) * 64;
  const int bm = blockIdx.y * 128;
  const int bl = blockIdx.x * 128;
  const int l15 = lane & 15, l4 = lane >> 4;

  f32x4 acc[4][4] = {};

  const int xlp = (tid & 63) * 2;
  const int xko = tid >> 6;

  for (int k0 = 0; k0 < KPAD; k0 += 32) {
    __syncthreads();
#pragma unroll
    for (int p = 0; p < 2; ++p) {
      int i = tid + p * 256;
      int m = i >> 2, k8 = (i & 3) * 8;
      *(half8*)&sA[0][m][k8] = *(const half8*)&Ah[(size_t)(bm + m) * KPAD + k0 + k8];
      *(half8*)&sA[1][m][k8] = *(const half8*)&Al[(size_t)(bm + m) * KPAD + k0 + k8];
    }
    {
      int gl = bl + xlp;
      int kb = k0 + xko * 8;
#pragma unroll
      for (int buf = 0; buf < 2; ++buf) {
        const _Float16* Xp = buf ? Xl : Xh;
        unsigned int v[8];
#pragma unroll
        for (int j = 0; j < 8; ++j)
          v[j] = *(const unsigned int*)&Xp[(size_t)(kb + j) * L + gl];
        short8 lo, hi;
#pragma unroll
        for (int j = 0; j < 8; ++j) {
          lo[j] = (short)(v[j] & 0xFFFFu);
          hi[j] = (short)(v[j] >> 16);
        }
        *(short8*)&sX[buf][xko][xlp][0] = lo;
        *(short8*)&sX[buf][xko][xlp + 1][0] = hi;
      }
    }
    __syncthreads();
    half8 afh[4], afl[4], bfh[4], bfl[4];
#pragma unroll
    for (int mi = 0; mi < 4; ++mi) {
      afh[mi] = *(half8*)&sA[0][wm + mi * 16 + l15][l4 * 8];
      afl[mi] = *(half8*)&sA[1][wm + mi * 16 + l15][l4 * 8];
    }
#pragma unroll
    for (int ni = 0; ni < 4; ++ni) {
      bfh[ni] = *(half8*)&sX[0][l4][wn + ni * 16 + l15][0];
      bfl[ni] = *(half8*)&sX[1][l4][wn + ni * 16 + l15][0];
    }
#pragma unroll
    for (int mi = 0; mi < 4; ++mi)
#pragma unroll
      for (int ni = 0; ni < 4; ++ni) {
        acc[mi][ni] = __builtin_amdgcn_mfma_f32_16x16x32_f16(afh[mi], bfh[ni],
                                                             acc[mi][ni], 0, 0, 0);
        acc[mi][ni] = __builtin_amdgcn_mfma_f32_16x16x32_f16(afh[mi], bfl[ni],
                                                             acc[mi][ni], 0, 0, 0);
        acc[mi][ni] = __builtin_amdgcn_mfma_f32_16x16x32_f16(afl[mi], bfh[ni],
                                                             acc[mi][ni], 0, 0, 0);
      }
  }
#pragma unroll
  for (int mi = 0; mi < 4; ++mi) {
    int row0 = bm + wm + mi * 16 + l4 * 4;
#pragma unroll
    for (int ni = 0; ni < 4; ++ni) {
      int col = bl + wn + ni * 16 + l15;
#pragma unroll
      for (int r = 0; r < 4; ++r) {
        int row = row0 + r;
        if (row < NN)
          split_f16(acc[mi][ni][r], &Gh[(size_t)row * L + col],
                    &Gl[(size_t)row * L + col]);
      }
    }
  }
}

// -------- build Xs: all 12 steps' x, octet-major [n][t][b][8] (j=0 only) -----
__global__ __launch_bounds__(256) void srcall_kernel(const float* __restrict__ src,
                                                     _Float16* __restrict__ Xsh,
                                                     _Float16* __restrict__ Xsl) {
  int i = blockIdx.x * 256 + threadIdx.x;
  if (i >= NN * BB * TT) return;
  int t = i % TT;
  int nb = i / TT;
  int b = nb & 63, n = nb >> 6;
  float v = src[((size_t)b * TT + t) * NN + n];
  size_t idx = (size_t)n * (TT * 512) + (size_t)t * 512 + (size_t)b * 8;
  split_f16(v, &Xsh[idx], &Xsl[idx]);
}

// -------- fused per-node gconv: monolithic W-gen in LDS + MFMA ---------------
// All operand buffers octet-major per node: [n][ko][b][8], channel = ko*8+j.
// K regions: [0,XSPLIT) IX; [XSPLIT,CS) IZ; [CS,CS+XSPLIT) DX; [CS+XSPLIT,KD) DZ.
// OW: o-tile width per block (32): grid (COUT/OW, NN). Smaller W LDS ->
// higher occupancy for the latency-bound fetch phase (round-13/14 lever,
// no added barriers). W LDS holds only KD/8 octets (k >= KD structurally 0).
// GATE: o_global<64 -> z-half writes z*h into XA (=Xz); else r -> ZRout.
// !GATE: GRU update, writes h-state + split-f16 h into XA.
template <int CS, int CIN, int XSPLIT, int OW, bool GATE>
__global__ __launch_bounds__(256) void gconv_fused(
    const _Float16* __restrict__ IXh, const _Float16* __restrict__ IXl, int sIX, int oIX,
    const _Float16* __restrict__ IZh, const _Float16* __restrict__ IZl, int sIZ, int oIZ,
    const _Float16* __restrict__ DXh, const _Float16* __restrict__ DXl, int sDX, int oDX,
    const _Float16* __restrict__ DZh, const _Float16* __restrict__ DZl, int sDZ, int oDZ,
    const float* __restrict__ E, const float* __restrict__ wpool,
    const float* __restrict__ bpool, const float* __restrict__ ZRin,
    float* __restrict__ hstate, float* __restrict__ ZRout,
    _Float16* __restrict__ XAh, _Float16* __restrict__ XAl, int csA, int cbA) {
  constexpr int COUT = GATE ? 128 : 64;
  constexpr int KD = 2 * CS;
  constexpr int KP = (KD + 31) & ~31;  // 160 / 256 (MFMA loop extent)
  constexpr int KOW = KD / 8;          // 18 / 32 (W octets actually stored)
  constexpr int NT = OW / 32;          // n-tiles per wave (wave covers 32 b x OW/2 o)
  const int n = blockIdx.y;
  const int och = blockIdx.x * OW;
  const int tid = threadIdx.x;
  const int lane = tid & 63, wid = tid >> 6;
  const int wm = (wid & 1) * 32;
  const int wn = (wid >> 1) * (OW / 2);
  const int l15 = lane & 15, l4 = lane >> 4;

  __shared__ float sE[EMB];
  __shared__ float sB[OW];
  __shared__ _Float16 sWh[KOW * OW * 8];
  __shared__ _Float16 sWl[KOW * OW * 8];

  if (tid < EMB) sE[tid] = E[n * EMB + tid];
  __syncthreads();

  // ---- W gen: octet layout sW[ko][o][8]; remap k -> weight row --------------
  {
    const int o = tid & (OW - 1);
    for (int ko = tid / OW; ko < KOW; ko += 256 / OW) {
      half8 hv, lv;
#pragma unroll
      for (int j = 0; j < 8; ++j) {
        const int k = ko * 8 + j;
        const int kk = (k >= CS) ? 1 : 0;
        const int kc = k - kk * CS;
        int ii;
        if (CS == CIN) ii = kc;
        else ii = (kc == 0) ? 0 : ((kc >= XSPLIT) ? kc - XSPLIT + 1 : -1);
        float w = 0.0f;
        if (ii >= 0) {
          const float* wp = wpool + ((size_t)kk * CIN + ii) * COUT + och + o;
#pragma unroll
          for (int d = 0; d < EMB; ++d)
            w += sE[d] * wp[(size_t)d * (2 * CIN * COUT)];
        }
        _Float16 hh = (_Float16)w;
        hv[j] = hh;
        lv[j] = (_Float16)(w - (float)hh);
      }
      *(half8*)&sWh[((size_t)ko * OW + o) * 8] = hv;
      *(half8*)&sWl[((size_t)ko * OW + o) * 8] = lv;
    }
    if (tid < OW) {
      float bb = 0.0f;
#pragma unroll
      for (int d = 0; d < EMB; ++d) bb += sE[d] * bpool[d * COUT + och + tid];
      sB[tid] = bb;
    }
  }
  __syncthreads();

  // ---- MFMA: A-fragments coalesced half8 from octet-major global ------------
  const size_t bIX = (size_t)n * sIX + (size_t)oIX * 512;
  const size_t bIZ = (size_t)n * sIZ + (size_t)oIZ * 512;
  const size_t bDX = (size_t)n * sDX + (size_t)oDX * 512;
  const size_t bDZ = (size_t)n * sDZ + (size_t)oDZ * 512;
  f32x4 acc[2][NT] = {};
  for (int k0 = 0; k0 < KP; k0 += 32) {
    const int kq = k0 + l4 * 8;
    half8 ah[2], al[2];
#pragma unroll
    for (int mt = 0; mt < 2; ++mt) {
      const int b = wm + mt * 16 + l15;
      if (kq < XSPLIT) {
        const size_t o = bIX + (size_t)(kq >> 3) * 512 + (size_t)b * 8;
        ah[mt] = *(const half8*)&IXh[o];
        al[mt] = *(const half8*)&IXl[o];
      } else if (kq < CS) {
        const size_t o = bIZ + (size_t)((kq - XSPLIT) >> 3) * 512 + (size_t)b * 8;
        ah[mt] = *(const half8*)&IZh[o];
        al[mt] = *(const half8*)&IZl[o];
      } else if (kq < CS + XSPLIT) {
        const size_t o = bDX + (size_t)((kq - CS) >> 3) * 512 + (size_t)b * 8;
        ah[mt] = *(const half8*)&DXh[o];
        al[mt] = *(const half8*)&DXl[o];
      } else if (kq < KD) {
        const size_t o =
            bDZ + (size_t)((kq - CS - XSPLIT) >> 3) * 512 + (size_t)b * 8;
        ah[mt] = *(const half8*)&DZh[o];
        al[mt] = *(const half8*)&DZl[o];
      } else {
        ah[mt] = (half8)(_Float16)0.f;
        al[mt] = (half8)(_Float16)0.f;
      }
    }
    const int koi = kq >> 3;
#pragma unroll
    for (int nt = 0; nt < NT; ++nt) {
      const int ol = wn + nt * 16 + l15;
      half8 bh, bl;
      if constexpr (KP == KD) {
        bh = *(const half8*)&sWh[((size_t)koi * OW + ol) * 8];
        bl = *(const half8*)&sWl[((size_t)koi * OW + ol) * 8];
      } else {
        if (kq < KD) {
          bh = *(const half8*)&sWh[((size_t)koi * OW + ol) * 8];
          bl = *(const half8*)&sWl[((size_t)koi * OW + ol) * 8];
        } else {
          bh = (half8)(_Float16)0.f;
          bl = (half8)(_Float16)0.f;
        }
      }
#pragma unroll
      for (int mt = 0; mt < 2; ++mt) {
        acc[mt][nt] =
            __builtin_amdgcn_mfma_f32_16x16x32_f16(ah[mt], bh, acc[mt][nt], 0, 0, 0);
        acc[mt][nt] =
            __builtin_amdgcn_mfma_f32_16x16x32_f16(ah[mt], bl, acc[mt][nt], 0, 0, 0);
        acc[mt][nt] =
            __builtin_amdgcn_mfma_f32_16x16x32_f16(al[mt], bh, acc[mt][nt], 0, 0, 0);
      }
    }
  }

  // ---- epilogue (octet-major writes) ----
#pragma unroll
  for (int mt = 0; mt < 2; ++mt) {
#pragma unroll
    for (int nt = 0; nt < NT; ++nt) {
      const int ol = wn + nt * 16 + l15;
      const int og = och + ol;  // global output channel
      const float bias = sB[ol];
#pragma unroll
      for (int r = 0; r < 4; ++r) {
        const int b = wm + mt * 16 + l4 * 4 + r;
        const size_t nb = (size_t)n * 64 + b;
        const float v = acc[mt][nt][r] + bias;
        if constexpr (GATE) {
          const float s = 1.0f / (1.0f + expf(-v));
          if (og < 64) {  // z half: write z*h compact (cand GEMM input)
            const float zh = s * hstate[nb * 64 + og];
            const int c2 = cbA + og;
            size_t ia = (size_t)n * 64 * csA + (size_t)(c2 >> 3) * 512 +
                        (size_t)b * 8 + (c2 & 7);
            split_f16(zh, &XAh[ia], &XAl[ia]);
          } else {  // r half
            ZRout[nb * 64 + (og - 64)] = s;
          }
        } else {
          const float hc = tanhf(v);
          const float rr = ZRin[nb * 64 + og];
          const float hold = hstate[nb * 64 + og];
          const float hn = rr * hold + (1.0f - rr) * hc;
          hstate[nb * 64 + og] = hn;
          const int cA = cbA + og;
          size_t ia = (size_t)n * 64 * csA + (size_t)(cA >> 3) * 512 +
                      (size_t)b * 8 + (cA & 7);
          split_f16(hn, &XAh[ia], &XAl[ia]);
        }
      }
    }
  }
}

// ---------------- output head ------------------------------------------------
__global__ __launch_bounds__(256) void head_kernel(const float* __restrict__ h1,
                                                   const float* __restrict__ cw,
                                                   const float* __restrict__ cb,
                                                   float* __restrict__ out) {
  int i = blockIdx.x * 256 + threadIdx.x;
  if (i >= BB * NN) return;
  int n = i % NN, b = i / NN;
  const float* hrow = h1 + ((size_t)n * 64 + b) * 64;
  float hv[64];
#pragma unroll
  for (int j = 0; j < 64; ++j) hv[j] = hrow[j];
  for (int o = 0; o < 12; ++o) {
    float s = cb[o];
#pragma unroll
    for (int j = 0; j < 64; ++j) s += hv[j] * cw[o * 64 + j];
    out[((size_t)b * 12 + o) * NN + n] = s;
  }
}

__global__ __launch_bounds__(256) void zero_f32(float* __restrict__ p, size_t count) {
  size_t i = (size_t)blockIdx.x * 256 + threadIdx.x;
  if (i < count) p[i] = 0.0f;
}
__global__ __launch_bounds__(256) void zero_u16(unsigned short* __restrict__ p,
                                                size_t count) {
  size_t i = (size_t)blockIdx.x * 256 + threadIdx.x;
  if (i < count) p[i] = 0;
}

extern "C" void kernel_launch(void* const* d_in, const int* in_sizes, int n_in,
                              void* d_out, int out_size, void* d_ws, size_t ws_size,
                              hipStream_t stream) {
  const float* src = (const float*)d_in[0];
  const float* E = (const float*)d_in[1];
  const float* w0g = (const float*)d_in[2];
  const float* b0g = (const float*)d_in[3];
  const float* w0c = (const float*)d_in[4];
  const float* b0c = (const float*)d_in[5];
  const float* w1g = (const float*)d_in[6];
  const float* b1g = (const float*)d_in[7];
  const float* w1c = (const float*)d_in[8];
  const float* b1c = (const float*)d_in[9];
  const float* cw = (const float*)d_in[10];
  const float* cb = (const float*)d_in[11];
  float* out = (float*)d_out;
  float* ws = (float*)d_ws;

  size_t off = 0;
  auto alloc = [&](size_t cnt) {  // cnt in floats
    float* p = ws + off;
    off += (cnt + 63) & ~(size_t)63;
    return p;
  };
  const int LS = TT * 512;  // 6144 (12 t-octets)
  const int L1 = 64 * 128;  // 8192 (16 octets)
  const int LZ = 64 * 64;   // 4096 (8 octets)
  _Float16* Ah = (_Float16*)alloc((size_t)KPAD * KPAD / 2);
  _Float16* Al = (_Float16*)alloc((size_t)KPAD * KPAD / 2);
  // contiguous zero span: Xs, Gx, X1a, Xz, Gl1, Gz (hi/lo pairs)
  _Float16* Xsh = (_Float16*)alloc((size_t)KPAD * LS / 2);
  _Float16* Xsl = (_Float16*)alloc((size_t)KPAD * LS / 2);
  _Float16* Gxh = (_Float16*)alloc((size_t)KPAD * LS / 2);
  _Float16* Gxl = (_Float16*)alloc((size_t)KPAD * LS / 2);
  _Float16* X1ah = (_Float16*)alloc((size_t)KPAD * L1 / 2);
  _Float16* X1al = (_Float16*)alloc((size_t)KPAD * L1 / 2);
  _Float16* Xzh = (_Float16*)alloc((size_t)KPAD * LZ / 2);
  _Float16* Xzl = (_Float16*)alloc((size_t)KPAD * LZ / 2);
  _Float16* Gl1h = (_Float16*)alloc((size_t)KPAD * L1 / 2);
  _Float16* Gl1l = (_Float16*)alloc((size_t)KPAD * L1 / 2);
  _Float16* Gzh = (_Float16*)alloc((size_t)KPAD * LZ / 2);
  _Float16* Gzl = (_Float16*)alloc((size_t)KPAD * LZ / 2);
  float* ZR = alloc((size_t)NN * BB * 64);
  float* h0 = alloc((size_t)NN * BB * 64);
  float* h1 = alloc((size_t)NN * BB * 64);
  if (off * sizeof(float) > ws_size) return;  // ws too small: fail loud (zeros)

  adj_kernel<<<NN, 256, 0, stream>>>(E, Ah, Al);
  {
    size_t cx = (size_t)2 * KPAD * (LS + LS + L1 + LZ + L1 + LZ);  // halves
    size_t chh = (size_t)2 * NN * BB * 64;  // floats (h0,h1 contiguous)
    zero_u16<<<(int)((cx + 255) / 256), 256, 0, stream>>>((unsigned short*)Xsh, cx);
    zero_f32<<<(int)((chh + 255) / 256), 256, 0, stream>>>(h0, chh);
  }
  // Pre-loop: Gx = A @ Xs  (all 12 steps' x diffused, once)
  srcall_kernel<<<(NN * BB * TT + 255) / 256, 256, 0, stream>>>(src, Xsh, Xsl);
  mfma_gemm3<<<dim3(LS / 128, 7), 256, 0, stream>>>(Ah, Al, Xsh, Xsl, Gxh, Gxl, LS);

  const int gx1 = L1 / 128;  // 64
  const int gxz = LZ / 128;  // 32
  for (int t = 0; t < TT; ++t) {
    // ---- layer 0: identity x <- Xs[t], h0 <- X1a octets 0-7;
    //      diffused x <- Gx[t], diffused h0 <- Gl1 octets 0-7 (step t-1) ----
    gconv_fused<72, 65, 8, 32, true><<<dim3(4, NN), 256, 0, stream>>>(
        Xsh, Xsl, LS, t, X1ah, X1al, L1, 0, Gxh, Gxl, LS, t, Gl1h, Gl1l, L1, 0,
        E, w0g, b0g, nullptr, h0, ZR, Xzh, Xzl, 64, 0);
    mfma_gemm3<<<dim3(gxz, 7), 256, 0, stream>>>(Ah, Al, Xzh, Xzl, Gzh, Gzl, LZ);
    gconv_fused<72, 65, 8, 32, false><<<dim3(2, NN), 256, 0, stream>>>(
        Xsh, Xsl, LS, t, Xzh, Xzl, LZ, 0, Gxh, Gxl, LS, t, Gzh, Gzl, LZ, 0,
        E, w0c, b0c, ZR, h0, nullptr, X1ah, X1al, 128, 0);
    // ---- layer 1: identity h0 <- X1a oct 0-7, h1 <- X1a oct 8-15 ----
    mfma_gemm3<<<dim3(gx1, 7), 256, 0, stream>>>(Ah, Al, X1ah, X1al, Gl1h, Gl1l, L1);
    gconv_fused<128, 128, 64, 32, true><<<dim3(4, NN), 256, 0, stream>>>(
        X1ah, X1al, L1, 0, X1ah, X1al, L1, 8, Gl1h, Gl1l, L1, 0, Gl1h, Gl1l, L1, 8,
        E, w1g, b1g, nullptr, h1, ZR, Xzh, Xzl, 64, 0);
    mfma_gemm3<<<dim3(gxz, 7), 256, 0, stream>>>(Ah, Al, Xzh, Xzl, Gzh, Gzl, LZ);
    gconv_fused<128, 128, 64, 32, false><<<dim3(2, NN), 256, 0, stream>>>(
        X1ah, X1al, L1, 0, Xzh, Xzl, LZ, 0, Gl1h, Gl1l, L1, 0, Gzh, Gzl, LZ, 0,
        E, w1c, b1c, ZR, h1, nullptr, X1ah, X1al, 128, 64);
  }
  head_kernel<<<(BB * NN + 255) / 256, 256, 0, stream>>>(h1, cw, cb, out);
}

// Round 16
// 3992.277 us; speedup vs baseline: 1.2818x; 1.0431x over previous
//
#include <hip/hip_runtime.h>
#include <cstddef>

#define NN 883
#define BB 64
#define TT 12
#define EMB 10
#define KPAD 896  // node dim padded to multiple of 128

typedef short short8 __attribute__((ext_vector_type(8)));
typedef _Float16 half8 __attribute__((ext_vector_type(8)));
typedef float f32x4 __attribute__((ext_vector_type(4)));

__device__ __forceinline__ void split_f16(float v, _Float16* hp, _Float16* lp) {
  _Float16 h = (_Float16)v;
  *hp = h;
  *lp = (_Float16)(v - (float)h);
}

// -------- adjacency: A = softmax(relu(E E^T), axis=1), emitted as f16 hi/lo --
__global__ __launch_bounds__(256) void adj_kernel(const float* __restrict__ E,
                                                  _Float16* __restrict__ Ah,
                                                  _Float16* __restrict__ Al) {
  const int n = blockIdx.x;
  const int tid = threadIdx.x;
  __shared__ float sE[EMB];
  __shared__ float sred[256];
  if (tid < EMB) sE[tid] = E[n * EMB + tid];
  __syncthreads();
  float d[4];
  float lmax = 0.0f;
#pragma unroll
  for (int q = 0; q < 4; ++q) {
    int m = tid + q * 256;
    d[q] = 0.0f;
    if (m < NN) {
      float s = 0.0f;
#pragma unroll
      for (int e = 0; e < EMB; ++e) s += sE[e] * E[m * EMB + e];
      d[q] = fmaxf(s, 0.0f);
      lmax = fmaxf(lmax, d[q]);
    }
  }
  sred[tid] = lmax;
  __syncthreads();
  for (int s = 128; s > 0; s >>= 1) {
    if (tid < s) sred[tid] = fmaxf(sred[tid], sred[tid + s]);
    __syncthreads();
  }
  const float mx = sred[0];
  __syncthreads();
  float lsum = 0.0f;
#pragma unroll
  for (int q = 0; q < 4; ++q) {
    int m = tid + q * 256;
    if (m < NN) {
      d[q] = expf(d[q] - mx);
      lsum += d[q];
    }
  }
  sred[tid] = lsum;
  __syncthreads();
  for (int s = 128; s > 0; s >>= 1) {
    if (tid < s) sred[tid] += sred[tid + s];
    __syncthreads();
  }
  const float inv = 1.0f / sred[0];
#pragma unroll
  for (int q = 0; q < 4; ++q) {
    int m = tid + q * 256;
    if (m < KPAD) {
      float v = (m < NN) ? d[q] * inv : 0.0f;
      split_f16(v, &Ah[(size_t)n * KPAD + m], &Al[(size_t)n * KPAD + m]);
    }
  }
}

// -------- 3-term split-f16 MFMA GEMM; output written as split f16 ------------
__global__ __launch_bounds__(256) void mfma_gemm3(const _Float16* __restrict__ Ah,
                                                  const _Float16* __restrict__ Al,
                                                  const _Float16* __restrict__ Xh,
                                                  const _Float16* __restrict__ Xl,
                                                  _Float16* __restrict__ Gh,
                                                  _Float16* __restrict__ Gl, int L) {
  __shared__ _Float16 sA[2][128][40];
  __shared__ _Float16 sX[2][4][128][8];
  const int tid = threadIdx.x;
  const int lane = tid & 63;
  const int wid = tid >> 6;
  const int wm = (wid >> 1) * 64, wn = (wid & 1) * 64;
  const int bm = blockIdx.y * 128;
  const int bl = blockIdx.x * 128;
  const int l15 = lane & 15, l4 = lane >> 4;

  f32x4 acc[4][4] = {};

  const int xlp = (tid & 63) * 2;
  const int xko = tid >> 6;

  for (int k0 = 0; k0 < KPAD; k0 += 32) {
    __syncthreads();
#pragma unroll
    for (int p = 0; p < 2; ++p) {
      int i = tid + p * 256;
      int m = i >> 2, k8 = (i & 3) * 8;
      *(half8*)&sA[0][m][k8] = *(const half8*)&Ah[(size_t)(bm + m) * KPAD + k0 + k8];
      *(half8*)&sA[1][m][k8] = *(const half8*)&Al[(size_t)(bm + m) * KPAD + k0 + k8];
    }
    {
      int gl = bl + xlp;
      int kb = k0 + xko * 8;
#pragma unroll
      for (int buf = 0; buf < 2; ++buf) {
        const _Float16* Xp = buf ? Xl : Xh;
        unsigned int v[8];
#pragma unroll
        for (int j = 0; j < 8; ++j)
          v[j] = *(const unsigned int*)&Xp[(size_t)(kb + j) * L + gl];
        short8 lo, hi;
#pragma unroll
        for (int j = 0; j < 8; ++j) {
          lo[j] = (short)(v[j] & 0xFFFFu);
          hi[j] = (short)(v[j] >> 16);
        }
        *(short8*)&sX[buf][xko][xlp][0] = lo;
        *(short8*)&sX[buf][xko][xlp + 1][0] = hi;
      }
    }
    __syncthreads();
    half8 afh[4], afl[4], bfh[4], bfl[4];
#pragma unroll
    for (int mi = 0; mi < 4; ++mi) {
      afh[mi] = *(half8*)&sA[0][wm + mi * 16 + l15][l4 * 8];
      afl[mi] = *(half8*)&sA[1][wm + mi * 16 + l15][l4 * 8];
    }
#pragma unroll
    for (int ni = 0; ni < 4; ++ni) {
      bfh[ni] = *(half8*)&sX[0][l4][wn + ni * 16 + l15][0];
      bfl[ni] = *(half8*)&sX[1][l4][wn + ni * 16 + l15][0];
    }
#pragma unroll
    for (int mi = 0; mi < 4; ++mi)
#pragma unroll
      for (int ni = 0; ni < 4; ++ni) {
        acc[mi][ni] = __builtin_amdgcn_mfma_f32_16x16x32_f16(afh[mi], bfh[ni],
                                                             acc[mi][ni], 0, 0, 0);
        acc[mi][ni] = __builtin_amdgcn_mfma_f32_16x16x32_f16(afh[mi], bfl[ni],
                                                             acc[mi][ni], 0, 0, 0);
        acc[mi][ni] = __builtin_amdgcn_mfma_f32_16x16x32_f16(afl[mi], bfh[ni],
                                                             acc[mi][ni], 0, 0, 0);
      }
  }
#pragma unroll
  for (int mi = 0; mi < 4; ++mi) {
    int row0 = bm + wm + mi * 16 + l4 * 4;
#pragma unroll
    for (int ni = 0; ni < 4; ++ni) {
      int col = bl + wn + ni * 16 + l15;
#pragma unroll
      for (int r = 0; r < 4; ++r) {
        int row = row0 + r;
        if (row < NN)
          split_f16(acc[mi][ni][r], &Gh[(size_t)row * L + col],
                    &Gl[(size_t)row * L + col]);
      }
    }
  }
}

// -------- build Xs: all 12 steps' x, octet-major [n][t][b][8] (j=0 only) -----
__global__ __launch_bounds__(256) void srcall_kernel(const float* __restrict__ src,
                                                     _Float16* __restrict__ Xsh,
                                                     _Float16* __restrict__ Xsl) {
  int i = blockIdx.x * 256 + threadIdx.x;
  if (i >= NN * BB * TT) return;
  int t = i % TT;
  int nb = i / TT;
  int b = nb & 63, n = nb >> 6;
  float v = src[((size_t)b * TT + t) * NN + n];
  size_t idx = (size_t)n * (TT * 512) + (size_t)t * 512 + (size_t)b * 8;
  split_f16(v, &Xsh[idx], &Xsl[idx]);
}

// -------- fused per-node gconv: monolithic W-gen in LDS + MFMA ---------------
// All operand buffers octet-major per node: [n][ko][b][8], channel = ko*8+j.
// K regions: [0,XSPLIT) IX; [XSPLIT,CS) IZ; [CS,CS+XSPLIT) DX; [CS+XSPLIT,KD) DZ.
// OW: o-tile width per block; C = COUT/OW o-chunks per node.
// 1D grid with XCD swizzle: id = (n%8) + 8*(C*(n/8) + oc) puts all C chunks
// of node n on the SAME XCD (linear id % 8 -> XCD round-robin heuristic), so
// the node's X/G rows are fetched into one L2 once, not C times.
// GATE: o_global<64 -> z-half writes z*h into XA (=Xz); else r -> ZRout.
// !GATE: GRU update, writes h-state + split-f16 h into XA.
template <int CS, int CIN, int XSPLIT, int OW, bool GATE>
__global__ __launch_bounds__(256) void gconv_fused(
    const _Float16* __restrict__ IXh, const _Float16* __restrict__ IXl, int sIX, int oIX,
    const _Float16* __restrict__ IZh, const _Float16* __restrict__ IZl, int sIZ, int oIZ,
    const _Float16* __restrict__ DXh, const _Float16* __restrict__ DXl, int sDX, int oDX,
    const _Float16* __restrict__ DZh, const _Float16* __restrict__ DZl, int sDZ, int oDZ,
    const float* __restrict__ E, const float* __restrict__ wpool,
    const float* __restrict__ bpool, const float* __restrict__ ZRin,
    float* __restrict__ hstate, float* __restrict__ ZRout,
    _Float16* __restrict__ XAh, _Float16* __restrict__ XAl, int csA, int cbA) {
  constexpr int COUT = GATE ? 128 : 64;
  constexpr int C = COUT / OW;         // o-chunks per node
  constexpr int KD = 2 * CS;
  constexpr int KP = (KD + 31) & ~31;  // 160 / 256 (MFMA loop extent)
  constexpr int KOW = KD / 8;          // 18 / 32 (W octets actually stored)
  constexpr int NT = OW / 32;          // n-tiles per wave
  // XCD swizzle decode
  const int bid = blockIdx.x;
  const int xcd = bid & 7;
  const int rest = bid >> 3;
  const int oc = rest % C;
  const int nq = rest / C;
  const int n = nq * 8 + xcd;
  if (n >= NN) return;
  const int och = oc * OW;
  const int tid = threadIdx.x;
  const int lane = tid & 63, wid = tid >> 6;
  const int wm = (wid & 1) * 32;
  const int wn = (wid >> 1) * (OW / 2);
  const int l15 = lane & 15, l4 = lane >> 4;

  __shared__ float sE[EMB];
  __shared__ float sB[OW];
  __shared__ _Float16 sWh[KOW * OW * 8];
  __shared__ _Float16 sWl[KOW * OW * 8];

  if (tid < EMB) sE[tid] = E[n * EMB + tid];
  __syncthreads();

  // ---- W gen: octet layout sW[ko][o][8]; remap k -> weight row --------------
  {
    const int o = tid & (OW - 1);
    for (int ko = tid / OW; ko < KOW; ko += 256 / OW) {
      half8 hv, lv;
#pragma unroll
      for (int j = 0; j < 8; ++j) {
        const int k = ko * 8 + j;
        const int kk = (k >= CS) ? 1 : 0;
        const int kc = k - kk * CS;
        int ii;
        if (CS == CIN) ii = kc;
        else ii = (kc == 0) ? 0 : ((kc >= XSPLIT) ? kc - XSPLIT + 1 : -1);
        float w = 0.0f;
        if (ii >= 0) {
          const float* wp = wpool + ((size_t)kk * CIN + ii) * COUT + och + o;
#pragma unroll
          for (int d = 0; d < EMB; ++d)
            w += sE[d] * wp[(size_t)d * (2 * CIN * COUT)];
        }
        _Float16 hh = (_Float16)w;
        hv[j] = hh;
        lv[j] = (_Float16)(w - (float)hh);
      }
      *(half8*)&sWh[((size_t)ko * OW + o) * 8] = hv;
      *(half8*)&sWl[((size_t)ko * OW + o) * 8] = lv;
    }
    if (tid < OW) {
      float bb = 0.0f;
#pragma unroll
      for (int d = 0; d < EMB; ++d) bb += sE[d] * bpool[d * COUT + och + tid];
      sB[tid] = bb;
    }
  }
  __syncthreads();

  // ---- MFMA: A-fragments coalesced half8 from octet-major global ------------
  const size_t bIX = (size_t)n * sIX + (size_t)oIX * 512;
  const size_t bIZ = (size_t)n * sIZ + (size_t)oIZ * 512;
  const size_t bDX = (size_t)n * sDX + (size_t)oDX * 512;
  const size_t bDZ = (size_t)n * sDZ + (size_t)oDZ * 512;
  f32x4 acc[2][NT] = {};
  for (int k0 = 0; k0 < KP; k0 += 32) {
    const int kq = k0 + l4 * 8;
    half8 ah[2], al[2];
#pragma unroll
    for (int mt = 0; mt < 2; ++mt) {
      const int b = wm + mt * 16 + l15;
      if (kq < XSPLIT) {
        const size_t o = bIX + (size_t)(kq >> 3) * 512 + (size_t)b * 8;
        ah[mt] = *(const half8*)&IXh[o];
        al[mt] = *(const half8*)&IXl[o];
      } else if (kq < CS) {
        const size_t o = bIZ + (size_t)((kq - XSPLIT) >> 3) * 512 + (size_t)b * 8;
        ah[mt] = *(const half8*)&IZh[o];
        al[mt] = *(const half8*)&IZl[o];
      } else if (kq < CS + XSPLIT) {
        const size_t o = bDX + (size_t)((kq - CS) >> 3) * 512 + (size_t)b * 8;
        ah[mt] = *(const half8*)&DXh[o];
        al[mt] = *(const half8*)&DXl[o];
      } else if (kq < KD) {
        const size_t o =
            bDZ + (size_t)((kq - CS - XSPLIT) >> 3) * 512 + (size_t)b * 8;
        ah[mt] = *(const half8*)&DZh[o];
        al[mt] = *(const half8*)&DZl[o];
      } else {
        ah[mt] = (half8)(_Float16)0.f;
        al[mt] = (half8)(_Float16)0.f;
      }
    }
    const int koi = kq >> 3;
#pragma unroll
    for (int nt = 0; nt < NT; ++nt) {
      const int ol = wn + nt * 16 + l15;
      half8 bh, bl;
      if constexpr (KP == KD) {
        bh = *(const half8*)&sWh[((size_t)koi * OW + ol) * 8];
        bl = *(const half8*)&sWl[((size_t)koi * OW + ol) * 8];
      } else {
        if (kq < KD) {
          bh = *(const half8*)&sWh[((size_t)koi * OW + ol) * 8];
          bl = *(const half8*)&sWl[((size_t)koi * OW + ol) * 8];
        } else {
          bh = (half8)(_Float16)0.f;
          bl = (half8)(_Float16)0.f;
        }
      }
#pragma unroll
      for (int mt = 0; mt < 2; ++mt) {
        acc[mt][nt] =
            __builtin_amdgcn_mfma_f32_16x16x32_f16(ah[mt], bh, acc[mt][nt], 0, 0, 0);
        acc[mt][nt] =
            __builtin_amdgcn_mfma_f32_16x16x32_f16(ah[mt], bl, acc[mt][nt], 0, 0, 0);
        acc[mt][nt] =
            __builtin_amdgcn_mfma_f32_16x16x32_f16(al[mt], bh, acc[mt][nt], 0, 0, 0);
      }
    }
  }

  // ---- epilogue (octet-major writes) ----
#pragma unroll
  for (int mt = 0; mt < 2; ++mt) {
#pragma unroll
    for (int nt = 0; nt < NT; ++nt) {
      const int ol = wn + nt * 16 + l15;
      const int og = och + ol;  // global output channel
      const float bias = sB[ol];
#pragma unroll
      for (int r = 0; r < 4; ++r) {
        const int b = wm + mt * 16 + l4 * 4 + r;
        const size_t nb = (size_t)n * 64 + b;
        const float v = acc[mt][nt][r] + bias;
        if constexpr (GATE) {
          const float s = 1.0f / (1.0f + expf(-v));
          if (og < 64) {  // z half: write z*h compact (cand GEMM input)
            const float zh = s * hstate[nb * 64 + og];
            const int c2 = cbA + og;
            size_t ia = (size_t)n * 64 * csA + (size_t)(c2 >> 3) * 512 +
                        (size_t)b * 8 + (c2 & 7);
            split_f16(zh, &XAh[ia], &XAl[ia]);
          } else {  // r half
            ZRout[nb * 64 + (og - 64)] = s;
          }
        } else {
          const float hc = tanhf(v);
          const float rr = ZRin[nb * 64 + og];
          const float hold = hstate[nb * 64 + og];
          const float hn = rr * hold + (1.0f - rr) * hc;
          hstate[nb * 64 + og] = hn;
          const int cA = cbA + og;
          size_t ia = (size_t)n * 64 * csA + (size_t)(cA >> 3) * 512 +
                      (size_t)b * 8 + (cA & 7);
          split_f16(hn, &XAh[ia], &XAl[ia]);
        }
      }
    }
  }
}

// ---------------- output head ------------------------------------------------
__global__ __launch_bounds__(256) void head_kernel(const float* __restrict__ h1,
                                                   const float* __restrict__ cw,
                                                   const float* __restrict__ cb,
                                                   float* __restrict__ out) {
  int i = blockIdx.x * 256 + threadIdx.x;
  if (i >= BB * NN) return;
  int n = i % NN, b = i / NN;
  const float* hrow = h1 + ((size_t)n * 64 + b) * 64;
  float hv[64];
#pragma unroll
  for (int j = 0; j < 64; ++j) hv[j] = hrow[j];
  for (int o = 0; o < 12; ++o) {
    float s = cb[o];
#pragma unroll
    for (int j = 0; j < 64; ++j) s += hv[j] * cw[o * 64 + j];
    out[((size_t)b * 12 + o) * NN + n] = s;
  }
}

__global__ __launch_bounds__(256) void zero_f32(float* __restrict__ p, size_t count) {
  size_t i = (size_t)blockIdx.x * 256 + threadIdx.x;
  if (i < count) p[i] = 0.0f;
}
__global__ __launch_bounds__(256) void zero_u16(unsigned short* __restrict__ p,
                                                size_t count) {
  size_t i = (size_t)blockIdx.x * 256 + threadIdx.x;
  if (i < count) p[i] = 0;
}

extern "C" void kernel_launch(void* const* d_in, const int* in_sizes, int n_in,
                              void* d_out, int out_size, void* d_ws, size_t ws_size,
                              hipStream_t stream) {
  const float* src = (const float*)d_in[0];
  const float* E = (const float*)d_in[1];
  const float* w0g = (const float*)d_in[2];
  const float* b0g = (const float*)d_in[3];
  const float* w0c = (const float*)d_in[4];
  const float* b0c = (const float*)d_in[5];
  const float* w1g = (const float*)d_in[6];
  const float* b1g = (const float*)d_in[7];
  const float* w1c = (const float*)d_in[8];
  const float* b1c = (const float*)d_in[9];
  const float* cw = (const float*)d_in[10];
  const float* cb = (const float*)d_in[11];
  float* out = (float*)d_out;
  float* ws = (float*)d_ws;

  size_t off = 0;
  auto alloc = [&](size_t cnt) {  // cnt in floats
    float* p = ws + off;
    off += (cnt + 63) & ~(size_t)63;
    return p;
  };
  const int LS = TT * 512;  // 6144 (12 t-octets)
  const int L1 = 64 * 128;  // 8192 (16 octets)
  const int LZ = 64 * 64;   // 4096 (8 octets)
  _Float16* Ah = (_Float16*)alloc((size_t)KPAD * KPAD / 2);
  _Float16* Al = (_Float16*)alloc((size_t)KPAD * KPAD / 2);
  // contiguous zero span: Xs, Gx, X1a, Xz, Gl1, Gz (hi/lo pairs)
  _Float16* Xsh = (_Float16*)alloc((size_t)KPAD * LS / 2);
  _Float16* Xsl = (_Float16*)alloc((size_t)KPAD * LS / 2);
  _Float16* Gxh = (_Float16*)alloc((size_t)KPAD * LS / 2);
  _Float16* Gxl = (_Float16*)alloc((size_t)KPAD * LS / 2);
  _Float16* X1ah = (_Float16*)alloc((size_t)KPAD * L1 / 2);
  _Float16* X1al = (_Float16*)alloc((size_t)KPAD * L1 / 2);
  _Float16* Xzh = (_Float16*)alloc((size_t)KPAD * LZ / 2);
  _Float16* Xzl = (_Float16*)alloc((size_t)KPAD * LZ / 2);
  _Float16* Gl1h = (_Float16*)alloc((size_t)KPAD * L1 / 2);
  _Float16* Gl1l = (_Float16*)alloc((size_t)KPAD * L1 / 2);
  _Float16* Gzh = (_Float16*)alloc((size_t)KPAD * LZ / 2);
  _Float16* Gzl = (_Float16*)alloc((size_t)KPAD * LZ / 2);
  float* ZR = alloc((size_t)NN * BB * 64);
  float* h0 = alloc((size_t)NN * BB * 64);
  float* h1 = alloc((size_t)NN * BB * 64);
  if (off * sizeof(float) > ws_size) return;  // ws too small: fail loud (zeros)

  adj_kernel<<<NN, 256, 0, stream>>>(E, Ah, Al);
  {
    size_t cx = (size_t)2 * KPAD * (LS + LS + L1 + LZ + L1 + LZ);  // halves
    size_t chh = (size_t)2 * NN * BB * 64;  // floats (h0,h1 contiguous)
    zero_u16<<<(int)((cx + 255) / 256), 256, 0, stream>>>((unsigned short*)Xsh, cx);
    zero_f32<<<(int)((chh + 255) / 256), 256, 0, stream>>>(h0, chh);
  }
  // Pre-loop: Gx = A @ Xs  (all 12 steps' x diffused, once)
  srcall_kernel<<<(NN * BB * TT + 255) / 256, 256, 0, stream>>>(src, Xsh, Xsl);
  mfma_gemm3<<<dim3(LS / 128, 7), 256, 0, stream>>>(Ah, Al, Xsh, Xsl, Gxh, Gxl, LS);

  const int gx1 = L1 / 128;  // 64
  const int gxz = LZ / 128;  // 32
  const int NQ8 = ((NN + 7) / 8) * 8;  // 888
  const int g_gate = NQ8 * 4;          // C=4 chunks (OW=32, COUT=128)
  const int g_cand = NQ8 * 2;          // C=2 chunks (OW=32, COUT=64)
  for (int t = 0; t < TT; ++t) {
    // ---- layer 0: identity x <- Xs[t], h0 <- X1a octets 0-7;
    //      diffused x <- Gx[t], diffused h0 <- Gl1 octets 0-7 (step t-1) ----
    gconv_fused<72, 65, 8, 32, true><<<g_gate, 256, 0, stream>>>(
        Xsh, Xsl, LS, t, X1ah, X1al, L1, 0, Gxh, Gxl, LS, t, Gl1h, Gl1l, L1, 0,
        E, w0g, b0g, nullptr, h0, ZR, Xzh, Xzl, 64, 0);
    mfma_gemm3<<<dim3(gxz, 7), 256, 0, stream>>>(Ah, Al, Xzh, Xzl, Gzh, Gzl, LZ);
    gconv_fused<72, 65, 8, 32, false><<<g_cand, 256, 0, stream>>>(
        Xsh, Xsl, LS, t, Xzh, Xzl, LZ, 0, Gxh, Gxl, LS, t, Gzh, Gzl, LZ, 0,
        E, w0c, b0c, ZR, h0, nullptr, X1ah, X1al, 128, 0);
    // ---- layer 1: identity h0 <- X1a oct 0-7, h1 <- X1a oct 8-15 ----
    mfma_gemm3<<<dim3(gx1, 7), 256, 0, stream>>>(Ah, Al, X1ah, X1al, Gl1h, Gl1l, L1);
    gconv_fused<128, 128, 64, 32, true><<<g_gate, 256, 0, stream>>>(
        X1ah, X1al, L1, 0, X1ah, X1al, L1, 8, Gl1h, Gl1l, L1, 0, Gl1h, Gl1l, L1, 8,
        E, w1g, b1g, nullptr, h1, ZR, Xzh, Xzl, 64, 0);
    mfma_gemm3<<<dim3(gxz, 7), 256, 0, stream>>>(Ah, Al, Xzh, Xzl, Gzh, Gzl, LZ);
    gconv_fused<128, 128, 64, 32, false><<<g_cand, 256, 0, stream>>>(
        X1ah, X1al, L1, 0, Xzh, Xzl, LZ, 0, Gl1h, Gl1l, L1, 0, Gzh, Gzl, LZ, 0,
        E, w1c, b1c, ZR, h1, nullptr, X1ah, X1al, 128, 64);
  }
  head_kernel<<<(BB * NN + 255) / 256, 256, 0, stream>>>(h1, cw, cb, out);
}